// Round 1
// baseline (259.870 us; speedup 1.0000x reference)
//
#include <hip/hip_runtime.h>
#include <hip/hip_bf16.h>

// ---------------- problem constants ----------------
#define HOP    1024
#define NFREQ  2049
#define NTIME  431
#define NSIG   8
#define SIGLEN 441000
#define PADW   2048           // n_fft/2 reflect pad
#define M_REAL 4098           // 2*2049 (cos rows then sin rows)
#define M_PAD  4224           // 33*128
#define N_REAL 3448           // 8*431
#define N_PAD  3456           // 27*128
#define K_DIM  4096

typedef unsigned short ushort_t;
typedef unsigned int   uint_t;
typedef __attribute__((ext_vector_type(8))) __bf16 bf16x8;
typedef __attribute__((ext_vector_type(4))) float  f32x4;

// float -> bf16 (round-to-nearest-even), bit-level (no header struct poking)
__device__ __forceinline__ ushort_t f2bf(float f) {
    uint_t u = __builtin_bit_cast(uint_t, f);
    u = (u + 0x7FFFu + ((u >> 16) & 1u)) >> 16;
    return (ushort_t)u;
}

// ---------------- pack filters into A (bf16, K-major, M padded) ----------------
__global__ __launch_bounds__(256) void build_A_kernel(
        const float* __restrict__ cosf, const float* __restrict__ sinf,
        ushort_t* __restrict__ A) {
    const long ntask = (long)M_PAD * K_DIM / 8;
    const long stride = (long)gridDim.x * blockDim.x;
    for (long task = (long)blockIdx.x * blockDim.x + threadIdx.x; task < ntask; task += stride) {
        const long e = task * 8;
        const int m = (int)(e >> 12);        // /4096
        const int k = (int)(e & 4095);
        alignas(16) ushort_t v[8];
        if (m < M_REAL) {
            const float* src = (m < NFREQ)
                ? cosf + ((long)m << 12) + k
                : sinf + ((long)(m - NFREQ) << 12) + k;
            const float4 a = reinterpret_cast<const float4*>(src)[0];
            const float4 b = reinterpret_cast<const float4*>(src)[1];
            v[0]=f2bf(a.x); v[1]=f2bf(a.y); v[2]=f2bf(a.z); v[3]=f2bf(a.w);
            v[4]=f2bf(b.x); v[5]=f2bf(b.y); v[6]=f2bf(b.z); v[7]=f2bf(b.w);
        } else {
            #pragma unroll
            for (int j = 0; j < 8; ++j) v[j] = 0;
        }
        *reinterpret_cast<uint4*>(A + e) = *reinterpret_cast<const uint4*>(v);
    }
}

// ---------------- materialize frames into B (bf16, K-major, N padded) ----------------
__global__ __launch_bounds__(256) void build_B_kernel(
        const float* __restrict__ x, ushort_t* __restrict__ B) {
    const long ntask = (long)N_PAD * K_DIM / 8;
    const long stride = (long)gridDim.x * blockDim.x;
    for (long task = (long)blockIdx.x * blockDim.x + threadIdx.x; task < ntask; task += stride) {
        const long e = task * 8;
        const int n = (int)(e >> 12);
        const int k = (int)(e & 4095);
        alignas(16) ushort_t v[8];
        if (n < N_REAL) {
            const int s = n / NTIME;
            const int t = n - s * NTIME;
            const float* xs = x + (long)s * SIGLEN;
            const int p0 = t * HOP + k - PADW;
            #pragma unroll
            for (int j = 0; j < 8; ++j) {
                int p = p0 + j;
                if (p < 0) p = -p;
                else if (p >= SIGLEN) p = 2 * SIGLEN - 2 - p;
                v[j] = f2bf(xs[p]);
            }
        } else {
            #pragma unroll
            for (int j = 0; j < 8; ++j) v[j] = 0;
        }
        *reinterpret_cast<uint4*>(B + e) = *reinterpret_cast<const uint4*>(v);
    }
}

// ---------------- async global -> LDS (16B per lane, wave-uniform LDS base) ----------------
__device__ __forceinline__ void gload_lds16(const ushort_t* g, ushort_t* l) {
    __builtin_amdgcn_global_load_lds(
        (const __attribute__((address_space(1))) void*)g,
        (__attribute__((address_space(3))) void*)l,
        16, 0, 0);
}

// ---------------- m97-structure 128x128 bf16 GEMM, epilogue scatters to STFT layout ----------------
__global__ __launch_bounds__(256) void stft_gemm(
        const ushort_t* __restrict__ A, const ushort_t* __restrict__ B,
        float* __restrict__ out) {
    __shared__ alignas(16) ushort_t As[128 * 32];
    __shared__ alignas(16) ushort_t Bs[128 * 32];

    const int tid  = threadIdx.x;
    const int lane = tid & 63;
    const int wave = tid >> 6;
    const int wm   = wave & 1;   // 2x2 wave grid, each wave owns 64x64
    const int wn   = wave >> 1;
    const int bm   = blockIdx.x;
    const int bn   = blockIdx.y;

    const ushort_t* Abase = A + ((long)bm * 128) * K_DIM;
    const ushort_t* Bbase = B + ((long)bn * 128) * K_DIM;

    // staging pattern: 512 groups of 8 bf16; thread t handles groups t and t+256
    const int r0 = tid >> 2;           const int c0 = (tid & 3) * 8;
    const int r1 = (tid + 256) >> 2;   const int c1 = ((tid + 256) & 3) * 8;
    const int ldsb0 = (tid & 192) * 8;           // wave-uniform LDS elem base, j=0
    const int ldsb1 = ((tid & 192) + 256) * 8;   // j=1

    f32x4 acc[4][4] = {};

    const int lrow = lane & 15;
    const int kgrp = (lane >> 4) * 8;

    for (int kt = 0; kt < K_DIM / 32; ++kt) {
        const ushort_t* Ak = Abase + kt * 32;
        const ushort_t* Bk = Bbase + kt * 32;
        gload_lds16(Ak + (long)r0 * K_DIM + c0, As + ldsb0);
        gload_lds16(Ak + (long)r1 * K_DIM + c1, As + ldsb1);
        gload_lds16(Bk + (long)r0 * K_DIM + c0, Bs + ldsb0);
        gload_lds16(Bk + (long)r1 * K_DIM + c1, Bs + ldsb1);
        __syncthreads();   // compiler drains vmcnt before s_barrier

        bf16x8 af[4], bfr[4];
        #pragma unroll
        for (int i = 0; i < 4; ++i)
            af[i] = *reinterpret_cast<const bf16x8*>(&As[(wm * 64 + i * 16 + lrow) * 32 + kgrp]);
        #pragma unroll
        for (int j = 0; j < 4; ++j)
            bfr[j] = *reinterpret_cast<const bf16x8*>(&Bs[(wn * 64 + j * 16 + lrow) * 32 + kgrp]);

        #pragma unroll
        for (int i = 0; i < 4; ++i)
            #pragma unroll
            for (int j = 0; j < 4; ++j)
                acc[i][j] = __builtin_amdgcn_mfma_f32_16x16x32_bf16(af[i], bfr[j], acc[i][j], 0, 0, 0);
        __syncthreads();
    }

    // epilogue: C[m][n] -> out[((s*2049 + k)*431 + t)*2 + ri]
    // verified C/D layout: col = lane&15, row = (lane>>4)*4 + reg
    const int mg_base = bm * 128 + wm * 64;
    const int ng_base = bn * 128 + wn * 64;
    const int row_off = (lane >> 4) * 4;
    const int col_off = lane & 15;

    #pragma unroll
    for (int j = 0; j < 4; ++j) {
        const int ng = ng_base + j * 16 + col_off;
        if (ng >= N_REAL) continue;
        const int s = ng / NTIME;
        const int t = ng - s * NTIME;
        #pragma unroll
        for (int i = 0; i < 4; ++i) {
            #pragma unroll
            for (int r = 0; r < 4; ++r) {
                const int m = mg_base + i * 16 + row_off + r;
                if (m < NFREQ) {
                    out[(((long)s * NFREQ + m) * NTIME + t) * 2 + 0] = acc[i][j][r];
                } else if (m < M_REAL) {
                    out[(((long)s * NFREQ + (m - NFREQ)) * NTIME + t) * 2 + 1] = acc[i][j][r];
                }
            }
        }
    }
}

extern "C" void kernel_launch(void* const* d_in, const int* in_sizes, int n_in,
                              void* d_out, int out_size, void* d_ws, size_t ws_size,
                              hipStream_t stream) {
    const float* x    = (const float*)d_in[0];
    const float* cosf = (const float*)d_in[1];
    const float* sinf = (const float*)d_in[2];
    float* out = (float*)d_out;

    ushort_t* A = (ushort_t*)d_ws;                       // 4224*4096*2  = 34.6 MB
    ushort_t* B = A + (long)M_PAD * K_DIM;               // 3456*4096*2  = 28.3 MB

    build_A_kernel<<<2048, 256, 0, stream>>>(cosf, sinf, A);
    build_B_kernel<<<2048, 256, 0, stream>>>(x, B);

    dim3 grid(M_PAD / 128, N_PAD / 128);   // 33 x 27
    stft_gemm<<<grid, 256, 0, stream>>>(A, B, out);
}

// Round 2
// 189.125 us; speedup vs baseline: 1.3741x; 1.3741x over previous
//
#include <hip/hip_runtime.h>
#include <hip/hip_bf16.h>

// ---------------- problem constants ----------------
#define HOP    1024
#define NFREQ  2049
#define NTIME  431
#define SIGLEN 441000
#define PADW   2048           // n_fft/2 reflect pad
#define M_REAL 4098           // 2*2049 (cos rows then sin rows)
#define M_PAD  4352           // 17*256
#define N_REAL 3448           // 8*431
#define N_PAD  3584           // 14*256
#define K_DIM  4096
#define NT     (K_DIM / 64)   // 64 K-tiles of BK=64

typedef unsigned short ushort_t;
typedef unsigned int   uint_t;
typedef __attribute__((ext_vector_type(8))) __bf16 bf16x8;
typedef __attribute__((ext_vector_type(4))) float  f32x4;

// float -> bf16 (round-to-nearest-even)
__device__ __forceinline__ ushort_t f2bf(float f) {
    uint_t u = __builtin_bit_cast(uint_t, f);
    u = (u + 0x7FFFu + ((u >> 16) & 1u)) >> 16;
    return (ushort_t)u;
}

// ---------------- pack filters into A (bf16, K-major, M padded) ----------------
__global__ __launch_bounds__(256) void build_A_kernel(
        const float* __restrict__ cosf, const float* __restrict__ sinf,
        ushort_t* __restrict__ A) {
    const long ntask = (long)M_PAD * K_DIM / 8;
    const long stride = (long)gridDim.x * blockDim.x;
    for (long task = (long)blockIdx.x * blockDim.x + threadIdx.x; task < ntask; task += stride) {
        const long e = task * 8;
        const int m = (int)(e >> 12);
        const int k = (int)(e & 4095);
        alignas(16) ushort_t v[8];
        if (m < M_REAL) {
            const float* src = (m < NFREQ)
                ? cosf + ((long)m << 12) + k
                : sinf + ((long)(m - NFREQ) << 12) + k;
            const float4 a = reinterpret_cast<const float4*>(src)[0];
            const float4 b = reinterpret_cast<const float4*>(src)[1];
            v[0]=f2bf(a.x); v[1]=f2bf(a.y); v[2]=f2bf(a.z); v[3]=f2bf(a.w);
            v[4]=f2bf(b.x); v[5]=f2bf(b.y); v[6]=f2bf(b.z); v[7]=f2bf(b.w);
        } else {
            #pragma unroll
            for (int j = 0; j < 8; ++j) v[j] = 0;
        }
        *reinterpret_cast<uint4*>(A + e) = *reinterpret_cast<const uint4*>(v);
    }
}

// ---------------- materialize frames into B (bf16, K-major, N padded) ----------------
__global__ __launch_bounds__(256) void build_B_kernel(
        const float* __restrict__ x, ushort_t* __restrict__ B) {
    const long ntask = (long)N_PAD * K_DIM / 8;
    const long stride = (long)gridDim.x * blockDim.x;
    for (long task = (long)blockIdx.x * blockDim.x + threadIdx.x; task < ntask; task += stride) {
        const long e = task * 8;
        const int n = (int)(e >> 12);
        const int k = (int)(e & 4095);
        alignas(16) ushort_t v[8];
        if (n < N_REAL) {
            const int s = n / NTIME;
            const int t = n - s * NTIME;
            const float* xs = x + (long)s * SIGLEN;
            const int p0 = t * HOP + k - PADW;
            #pragma unroll
            for (int j = 0; j < 8; ++j) {
                int p = p0 + j;
                if (p < 0) p = -p;
                else if (p >= SIGLEN) p = 2 * SIGLEN - 2 - p;
                v[j] = f2bf(xs[p]);
            }
        } else {
            #pragma unroll
            for (int j = 0; j < 8; ++j) v[j] = 0;
        }
        *reinterpret_cast<uint4*>(B + e) = *reinterpret_cast<const uint4*>(v);
    }
}

// ---------------- async global -> LDS (16B per lane, wave-uniform LDS base) ----------------
__device__ __forceinline__ void gload_lds16(const ushort_t* g, ushort_t* l) {
    __builtin_amdgcn_global_load_lds(
        (const __attribute__((address_space(1))) void*)g,
        (__attribute__((address_space(3))) void*)l,
        16, 0, 0);
}

__device__ __forceinline__ f32x4 MF(bf16x8 x, bf16x8 y, f32x4 c) {
    return __builtin_amdgcn_mfma_f32_16x16x32_bf16(x, y, c, 0, 0, 0);
}

#define SBAR()  __builtin_amdgcn_s_barrier()
#define SCHED() __builtin_amdgcn_sched_barrier(0)

// ---------------- 256x256 8-phase bf16 GEMM (T2+T3+T4+T5), STFT epilogue ----------------
__global__ __launch_bounds__(512, 2) void stft_gemm(
        const ushort_t* __restrict__ A, const ushort_t* __restrict__ B,
        float* __restrict__ out) {
    // [2 dbuf][256 rows][64 bf16 = 128B]; XOR-swizzled contents (see STAGE/FRAG)
    __shared__ alignas(16) ushort_t As[2][256 * 64];
    __shared__ alignas(16) ushort_t Bs[2][256 * 64];

    const int tid  = threadIdx.x;
    const int lane = tid & 63;
    const int wv   = tid >> 6;
    const int wm   = wv & 1;    // 2 (M) x 4 (N) wave grid; wave owns 128x64
    const int wn   = wv >> 1;
    const int bm   = blockIdx.x;
    const int bn   = blockIdx.y;

    const long Arow0 = (long)bm * 256;
    const long Brow0 = (long)bn * 256;

    // staging geometry: half-tile = 128 rows x 128B; thread covers rows rb and rb+64.
    // LDS dest is LINEAR (tid*16B); the XOR swizzle is applied to the GLOBAL source col.
    const int rb   = tid >> 3;                                        // 0..63
    const int scol = ((((tid & 7) << 4) ^ ((rb & 7) << 4)) >> 1);     // ushort offset in row
    const int ldsw = wv * 512;                                        // wave-uniform LDS base (ushorts)

    auto STAGE = [&](const ushort_t* __restrict__ G, long row0, int kt, ushort_t* half) {
        const ushort_t* g = G + (row0 + rb) * (long)K_DIM + kt * 64 + scol;
        gload_lds16(g, half + ldsw);                                  // rows 0..63 of half
        gload_lds16(g + (long)64 * K_DIM, half + 4096 + ldsw);        // rows 64..127
    };

    // fragment read: logical (row lr, k-step byte kb) with matching XOR swizzle
    const int lrow = lane & 15;
    const int kq   = (lane >> 4) << 4;   // 0/16/32/48 bytes within the 64B k-step
    auto FRAG = [&](const ushort_t* buf, int lr, int kb) -> bf16x8 {
        const char* p = reinterpret_cast<const char*>(buf)
                        + lr * 128 + ((kb + kq) ^ ((lr & 7) << 4));
        return *reinterpret_cast<const bf16x8*>(p);
    };

    f32x4 acc[8][4] = {};
    bf16x8 a[4][2], b0[2][2], b1[2][2];

    const int arow = wm * 128 + lrow;
    const int brow = wn * 64 + lrow;

    // ---- prologue: tile0 fully + tile1 minus A-h1 (A-h1 comes at (0,P1)) ----
    STAGE(A, Arow0,       0, As[0]);
    STAGE(A, Arow0 + 128, 0, As[0] + 8192);
    STAGE(B, Brow0,       0, Bs[0]);
    STAGE(B, Brow0 + 128, 0, Bs[0] + 8192);
    STAGE(B, Brow0,       1, Bs[1]);
    STAGE(B, Brow0 + 128, 1, Bs[1] + 8192);
    STAGE(A, Arow0,       1, As[1]);
    SCHED();
    asm volatile("s_waitcnt vmcnt(6)" ::: "memory");   // tile0 retired; 6 of tile1 in flight
    SBAR();
    SCHED();

    for (int t = 0; t < NT - 1; ++t) {
        const int cur = t & 1;
        const ushort_t* Ac = As[cur];
        const ushort_t* Bc = Bs[cur];
        ushort_t* An = As[cur ^ 1];
        ushort_t* Ao = As[cur];          // tile t+2 shares parity with t
        ushort_t* Bo = Bs[cur];
        const int kt1 = t + 1;
        const int kt2 = (t + 2 < NT) ? (t + 2) : (NT - 1);   // clamped phantom at the end

        // ================= P1 : reads A(mf0-3)+B(nf0-1) | stage A-h1(t+1) | MFMA Q00
        #pragma unroll
        for (int mf = 0; mf < 4; ++mf) {
            a[mf][0] = FRAG(Ac, arow + mf * 16, 0);
            a[mf][1] = FRAG(Ac, arow + mf * 16, 64);
        }
        #pragma unroll
        for (int nf = 0; nf < 2; ++nf) {
            b0[nf][0] = FRAG(Bc, brow + nf * 16, 0);
            b0[nf][1] = FRAG(Bc, brow + nf * 16, 64);
        }
        STAGE(A, Arow0 + 128, kt1, An + 8192);
        SCHED();
        SBAR();
        asm volatile("s_waitcnt lgkmcnt(0)" ::: "memory");
        SCHED();
        __builtin_amdgcn_s_setprio(1);
        #pragma unroll
        for (int mf = 0; mf < 4; ++mf)
            #pragma unroll
            for (int nf = 0; nf < 2; ++nf) {
                acc[mf][nf] = MF(a[mf][0], b0[nf][0], acc[mf][nf]);
                acc[mf][nf] = MF(a[mf][1], b0[nf][1], acc[mf][nf]);
            }
        __builtin_amdgcn_s_setprio(0);
        SCHED(); SBAR(); SCHED();

        // ================= P2 : reads B(nf2-3) | MFMA Q01
        #pragma unroll
        for (int nf = 0; nf < 2; ++nf) {
            b1[nf][0] = FRAG(Bc, brow + (nf + 2) * 16, 0);
            b1[nf][1] = FRAG(Bc, brow + (nf + 2) * 16, 64);
        }
        SCHED();
        SBAR();
        asm volatile("s_waitcnt lgkmcnt(0)" ::: "memory");
        SCHED();
        __builtin_amdgcn_s_setprio(1);
        #pragma unroll
        for (int mf = 0; mf < 4; ++mf)
            #pragma unroll
            for (int nf = 0; nf < 2; ++nf) {
                acc[mf][nf + 2] = MF(a[mf][0], b1[nf][0], acc[mf][nf + 2]);
                acc[mf][nf + 2] = MF(a[mf][1], b1[nf][1], acc[mf][nf + 2]);
            }
        __builtin_amdgcn_s_setprio(0);
        SCHED(); SBAR(); SCHED();

        // ================= P3 : reads A(mf4-7) | stage B-h0(t+2) | MFMA Q11
        #pragma unroll
        for (int mf = 0; mf < 4; ++mf) {
            a[mf][0] = FRAG(Ac, arow + (mf + 4) * 16, 0);
            a[mf][1] = FRAG(Ac, arow + (mf + 4) * 16, 64);
        }
        STAGE(B, Brow0, kt2, Bo);
        SCHED();
        SBAR();
        asm volatile("s_waitcnt lgkmcnt(0)" ::: "memory");
        SCHED();
        __builtin_amdgcn_s_setprio(1);
        #pragma unroll
        for (int mf = 0; mf < 4; ++mf)
            #pragma unroll
            for (int nf = 0; nf < 2; ++nf) {
                acc[mf + 4][nf + 2] = MF(a[mf][0], b1[nf][0], acc[mf + 4][nf + 2]);
                acc[mf + 4][nf + 2] = MF(a[mf][1], b1[nf][1], acc[mf + 4][nf + 2]);
            }
        __builtin_amdgcn_s_setprio(0);
        SCHED(); SBAR(); SCHED();

        // ================= P4 : stage B-h1(t+2), A-h0(t+2) | vmcnt(6) | MFMA Q10
        STAGE(B, Brow0 + 128, kt2, Bo + 8192);
        STAGE(A, Arow0,       kt2, Ao);
        SCHED();
        asm volatile("s_waitcnt vmcnt(6)" ::: "memory");  // tile t+1 fully retired
        SBAR();
        SCHED();
        __builtin_amdgcn_s_setprio(1);
        #pragma unroll
        for (int mf = 0; mf < 4; ++mf)
            #pragma unroll
            for (int nf = 0; nf < 2; ++nf) {
                acc[mf + 4][nf] = MF(a[mf][0], b0[nf][0], acc[mf + 4][nf]);
                acc[mf + 4][nf] = MF(a[mf][1], b0[nf][1], acc[mf + 4][nf]);
            }
        __builtin_amdgcn_s_setprio(0);
        SCHED(); SBAR(); SCHED();
    }

    // ---- epilogue compute: tile NT-1 from buf[1], no staging ----
    {
        const ushort_t* Ac = As[1];
        const ushort_t* Bc = Bs[1];
        #pragma unroll
        for (int mf = 0; mf < 4; ++mf) {
            a[mf][0] = FRAG(Ac, arow + mf * 16, 0);
            a[mf][1] = FRAG(Ac, arow + mf * 16, 64);
        }
        #pragma unroll
        for (int nf = 0; nf < 2; ++nf) {
            b0[nf][0] = FRAG(Bc, brow + nf * 16, 0);
            b0[nf][1] = FRAG(Bc, brow + nf * 16, 64);
            b1[nf][0] = FRAG(Bc, brow + (nf + 2) * 16, 0);
            b1[nf][1] = FRAG(Bc, brow + (nf + 2) * 16, 64);
        }
        #pragma unroll
        for (int mf = 0; mf < 4; ++mf)
            #pragma unroll
            for (int nf = 0; nf < 2; ++nf) {
                acc[mf][nf]     = MF(a[mf][0], b0[nf][0], acc[mf][nf]);
                acc[mf][nf]     = MF(a[mf][1], b0[nf][1], acc[mf][nf]);
                acc[mf][nf + 2] = MF(a[mf][0], b1[nf][0], acc[mf][nf + 2]);
                acc[mf][nf + 2] = MF(a[mf][1], b1[nf][1], acc[mf][nf + 2]);
            }
        #pragma unroll
        for (int mf = 0; mf < 4; ++mf) {
            a[mf][0] = FRAG(Ac, arow + (mf + 4) * 16, 0);
            a[mf][1] = FRAG(Ac, arow + (mf + 4) * 16, 64);
        }
        #pragma unroll
        for (int mf = 0; mf < 4; ++mf)
            #pragma unroll
            for (int nf = 0; nf < 2; ++nf) {
                acc[mf + 4][nf]     = MF(a[mf][0], b0[nf][0], acc[mf + 4][nf]);
                acc[mf + 4][nf]     = MF(a[mf][1], b0[nf][1], acc[mf + 4][nf]);
                acc[mf + 4][nf + 2] = MF(a[mf][0], b1[nf][0], acc[mf + 4][nf + 2]);
                acc[mf + 4][nf + 2] = MF(a[mf][1], b1[nf][1], acc[mf + 4][nf + 2]);
            }
    }

    // ---- C-write: C[m][n] -> out[((s*2049 + freq)*431 + t)*2 + ri] ----
    // C/D layout: col = lane&15 (N side), row = (lane>>4)*4 + reg (M side)
    const int row_off = (lane >> 4) << 2;
    const int col_off = lane & 15;
    const int mg_base = bm * 256 + wm * 128;
    const int ng_base = bn * 256 + wn * 64;

    #pragma unroll
    for (int nf = 0; nf < 4; ++nf) {
        const int ng = ng_base + nf * 16 + col_off;
        if (ng >= N_REAL) continue;
        const int s = ng / NTIME;
        const int tt = ng - s * NTIME;
        #pragma unroll
        for (int mf = 0; mf < 8; ++mf) {
            #pragma unroll
            for (int r = 0; r < 4; ++r) {
                const int m = mg_base + mf * 16 + row_off + r;
                if (m < NFREQ) {
                    out[(((long)s * NFREQ + m) * NTIME + tt) * 2 + 0] = acc[mf][nf][r];
                } else if (m < M_REAL) {
                    out[(((long)s * NFREQ + (m - NFREQ)) * NTIME + tt) * 2 + 1] = acc[mf][nf][r];
                }
            }
        }
    }
}

extern "C" void kernel_launch(void* const* d_in, const int* in_sizes, int n_in,
                              void* d_out, int out_size, void* d_ws, size_t ws_size,
                              hipStream_t stream) {
    const float* x    = (const float*)d_in[0];
    const float* cosf = (const float*)d_in[1];
    const float* sinf = (const float*)d_in[2];
    float* out = (float*)d_out;

    ushort_t* A = (ushort_t*)d_ws;                 // 4352*4096*2 = 35.7 MB
    ushort_t* B = A + (long)M_PAD * K_DIM;         // 3584*4096*2 = 29.4 MB

    build_A_kernel<<<2048, 256, 0, stream>>>(cosf, sinf, A);
    build_B_kernel<<<2048, 256, 0, stream>>>(x, B);

    dim3 grid(M_PAD / 256, N_PAD / 256);   // 17 x 14 = 238 blocks, ~1/CU
    stft_gemm<<<grid, 512, 0, stream>>>(A, B, out);
}

// Round 3
// 166.753 us; speedup vs baseline: 1.5584x; 1.1342x over previous
//
#include <hip/hip_runtime.h>
#include <hip/hip_bf16.h>

// ---------------- problem constants ----------------
#define HOP    1024
#define NFREQ  2049
#define NTIME  431
#define SIGLEN 441000
#define PADW   2048           // n_fft/2 reflect pad
#define M_REAL 4098           // 2*2049 (cos rows then sin rows)
#define M_PAD  4352           // 17*256
#define N_REAL 3448           // 8*431
#define N_PAD  3584           // 14*256
#define K_DIM  4096
#define NT     (K_DIM / 64)   // 64 K-tiles of BK=64

typedef unsigned short ushort_t;
typedef unsigned int   uint_t;
typedef __attribute__((ext_vector_type(8))) __bf16 bf16x8;
typedef __attribute__((ext_vector_type(4))) float  f32x4;

// float -> bf16 (round-to-nearest-even)
__device__ __forceinline__ ushort_t f2bf(float f) {
    uint_t u = __builtin_bit_cast(uint_t, f);
    u = (u + 0x7FFFu + ((u >> 16) & 1u)) >> 16;
    return (ushort_t)u;
}

// ---------------- pack filters into A (bf16, K-major, M padded) ----------------
__global__ __launch_bounds__(256) void build_A_kernel(
        const float* __restrict__ cosf, const float* __restrict__ sinf,
        ushort_t* __restrict__ A) {
    const long ntask = (long)M_PAD * K_DIM / 8;
    const long stride = (long)gridDim.x * blockDim.x;
    for (long task = (long)blockIdx.x * blockDim.x + threadIdx.x; task < ntask; task += stride) {
        const long e = task * 8;
        const int m = (int)(e >> 12);
        const int k = (int)(e & 4095);
        alignas(16) ushort_t v[8];
        if (m < M_REAL) {
            const float* src = (m < NFREQ)
                ? cosf + ((long)m << 12) + k
                : sinf + ((long)(m - NFREQ) << 12) + k;
            const float4 a = reinterpret_cast<const float4*>(src)[0];
            const float4 b = reinterpret_cast<const float4*>(src)[1];
            v[0]=f2bf(a.x); v[1]=f2bf(a.y); v[2]=f2bf(a.z); v[3]=f2bf(a.w);
            v[4]=f2bf(b.x); v[5]=f2bf(b.y); v[6]=f2bf(b.z); v[7]=f2bf(b.w);
        } else {
            #pragma unroll
            for (int j = 0; j < 8; ++j) v[j] = 0;
        }
        *reinterpret_cast<uint4*>(A + e) = *reinterpret_cast<const uint4*>(v);
    }
}

// ---------------- materialize frames into B (bf16, K-major, N padded) ----------------
__global__ __launch_bounds__(256) void build_B_kernel(
        const float* __restrict__ x, ushort_t* __restrict__ B) {
    const long ntask = (long)N_PAD * K_DIM / 8;
    const long stride = (long)gridDim.x * blockDim.x;
    for (long task = (long)blockIdx.x * blockDim.x + threadIdx.x; task < ntask; task += stride) {
        const long e = task * 8;
        const int n = (int)(e >> 12);
        const int k = (int)(e & 4095);
        alignas(16) ushort_t v[8];
        if (n < N_REAL) {
            const int s = n / NTIME;
            const int t = n - s * NTIME;
            const float* xs = x + (long)s * SIGLEN;
            const int p0 = t * HOP + k - PADW;
            #pragma unroll
            for (int j = 0; j < 8; ++j) {
                int p = p0 + j;
                if (p < 0) p = -p;
                else if (p >= SIGLEN) p = 2 * SIGLEN - 2 - p;
                v[j] = f2bf(xs[p]);
            }
        } else {
            #pragma unroll
            for (int j = 0; j < 8; ++j) v[j] = 0;
        }
        *reinterpret_cast<uint4*>(B + e) = *reinterpret_cast<const uint4*>(v);
    }
}

// ---------------- async global -> LDS (16B per lane, wave-uniform LDS base) ----------------
__device__ __forceinline__ void gload_lds16(const ushort_t* g, ushort_t* l) {
    __builtin_amdgcn_global_load_lds(
        (const __attribute__((address_space(1))) void*)g,
        (__attribute__((address_space(3))) void*)l,
        16, 0, 0);
}

__device__ __forceinline__ f32x4 MF(bf16x8 x, bf16x8 y, f32x4 c) {
    return __builtin_amdgcn_mfma_f32_16x16x32_bf16(x, y, c, 0, 0, 0);
}

#define SBAR()  __builtin_amdgcn_s_barrier()

// ---------------- 256x256 bf16 GEMM: counted-vmcnt dbuf, fine-grained lgkm overlap ----------------
__global__ __launch_bounds__(512, 2) void stft_gemm(
        const ushort_t* __restrict__ A, const ushort_t* __restrict__ B,
        float* __restrict__ out) {
    // [2 dbuf][256 rows][64 bf16 = 128B]; XOR-swizzled contents (see STAGE/FRAG)
    __shared__ alignas(16) ushort_t As[2][256 * 64];
    __shared__ alignas(16) ushort_t Bs[2][256 * 64];

    const int tid  = threadIdx.x;
    const int lane = tid & 63;
    const int wv   = tid >> 6;
    const int wm   = wv & 1;    // 2 (M) x 4 (N) wave grid; wave owns 128x64
    const int wn   = wv >> 1;
    const int bm   = blockIdx.x;
    const int bn   = blockIdx.y;

    const long Arow0 = (long)bm * 256;
    const long Brow0 = (long)bn * 256;

    // staging geometry: half-tile = 128 rows x 128B; thread covers rows rb and rb+64.
    // LDS dest is LINEAR (tid*16B); the XOR swizzle is applied to the GLOBAL source col.
    const int rb   = tid >> 3;                                        // 0..63
    const int scol = ((((tid & 7) << 4) ^ ((rb & 7) << 4)) >> 1);     // ushort offset in row
    const int ldsw = wv * 512;                                        // wave-uniform LDS base (ushorts)

    auto STAGE = [&](const ushort_t* __restrict__ G, long row0, int kt, ushort_t* half) {
        const ushort_t* g = G + (row0 + rb) * (long)K_DIM + kt * 64 + scol;
        gload_lds16(g, half + ldsw);                                  // rows 0..63 of half
        gload_lds16(g + (long)64 * K_DIM, half + 4096 + ldsw);        // rows 64..127
    };

    // fragment read: logical (row lr, k-step byte kb) with matching XOR swizzle
    const int lrow = lane & 15;
    const int kq   = (lane >> 4) << 4;   // 0/16/32/48 bytes within the 64B k-step
    auto FRAG = [&](const ushort_t* buf, int lr, int kb) -> bf16x8 {
        const char* p = reinterpret_cast<const char*>(buf)
                        + lr * 128 + ((kb + kq) ^ ((lr & 7) << 4));
        return *reinterpret_cast<const bf16x8*>(p);
    };

    f32x4 acc[8][4] = {};
    bf16x8 a[4][2], b0[2][2], b1[2][2];

    const int arow = wm * 128 + lrow;
    const int brow = wn * 64 + lrow;

    // ---- prologue: tile0 fully (8 loads) + tile1's B-h0,B-h1,A-h0 (6 loads) ----
    STAGE(A, Arow0,       0, As[0]);
    STAGE(A, Arow0 + 128, 0, As[0] + 8192);
    STAGE(B, Brow0,       0, Bs[0]);
    STAGE(B, Brow0 + 128, 0, Bs[0] + 8192);
    STAGE(B, Brow0,       1, Bs[1]);
    STAGE(B, Brow0 + 128, 1, Bs[1] + 8192);
    STAGE(A, Arow0,       1, As[1]);
    asm volatile("s_waitcnt vmcnt(6)" ::: "memory");   // tile0 retired; 6 of tile1 in flight
    SBAR();

    for (int t = 0; t < NT - 1; ++t) {
        const int cur = t & 1;
        const ushort_t* Ac = As[cur];
        const ushort_t* Bc = Bs[cur];
        ushort_t* An = As[cur ^ 1];
        ushort_t* Ao = As[cur];          // tile t+2 shares parity with t
        ushort_t* Bo = Bs[cur];
        const int kt1 = t + 1;
        const int kt2 = (t + 2 < NT) ? (t + 2) : (NT - 1);   // clamped phantom at the end

        // ===== P1: issue b0, a0-3, b1 reads | stage A-h1(t+1) | Q00 (fine-grained waits)
        #pragma unroll
        for (int nf = 0; nf < 2; ++nf) {
            b0[nf][0] = FRAG(Bc, brow + nf * 16, 0);
            b0[nf][1] = FRAG(Bc, brow + nf * 16, 64);
        }
        #pragma unroll
        for (int mf = 0; mf < 4; ++mf) {
            a[mf][0] = FRAG(Ac, arow + mf * 16, 0);
            a[mf][1] = FRAG(Ac, arow + mf * 16, 64);
        }
        #pragma unroll
        for (int nf = 0; nf < 2; ++nf) {
            b1[nf][0] = FRAG(Bc, brow + (nf + 2) * 16, 0);
            b1[nf][1] = FRAG(Bc, brow + (nf + 2) * 16, 64);
        }
        STAGE(A, Arow0 + 128, kt1, An + 8192);
        __builtin_amdgcn_s_setprio(1);
        #pragma unroll
        for (int mf = 0; mf < 4; ++mf)
            #pragma unroll
            for (int nf = 0; nf < 2; ++nf) {
                acc[mf][nf] = MF(a[mf][0], b0[nf][0], acc[mf][nf]);
                acc[mf][nf] = MF(a[mf][1], b0[nf][1], acc[mf][nf]);
            }
        __builtin_amdgcn_s_setprio(0);
        SBAR();

        // ===== P2: Q01 (b1 arrived during Q00) | then refill a[] with a4-7
        __builtin_amdgcn_s_setprio(1);
        #pragma unroll
        for (int mf = 0; mf < 4; ++mf)
            #pragma unroll
            for (int nf = 0; nf < 2; ++nf) {
                acc[mf][nf + 2] = MF(a[mf][0], b1[nf][0], acc[mf][nf + 2]);
                acc[mf][nf + 2] = MF(a[mf][1], b1[nf][1], acc[mf][nf + 2]);
            }
        __builtin_amdgcn_s_setprio(0);
        #pragma unroll
        for (int mf = 0; mf < 4; ++mf) {
            a[mf][0] = FRAG(Ac, arow + (mf + 4) * 16, 0);
            a[mf][1] = FRAG(Ac, arow + (mf + 4) * 16, 64);
        }
        SBAR();

        // ===== P3: Q11 (a4-7 delivering) | architectural drain before overwrites
        __builtin_amdgcn_s_setprio(1);
        #pragma unroll
        for (int mf = 0; mf < 4; ++mf)
            #pragma unroll
            for (int nf = 0; nf < 2; ++nf) {
                acc[mf + 4][nf + 2] = MF(a[mf][0], b1[nf][0], acc[mf + 4][nf + 2]);
                acc[mf + 4][nf + 2] = MF(a[mf][1], b1[nf][1], acc[mf + 4][nf + 2]);
            }
        __builtin_amdgcn_s_setprio(0);
        asm volatile("s_waitcnt lgkmcnt(0)" ::: "memory");  // all tile-t reads delivered
        SBAR();

        // ===== P4: stage B-h0,B-h1,A-h0(t+2) | Q10 (regs only) | counted vmcnt
        STAGE(B, Brow0,       kt2, Bo);
        STAGE(B, Brow0 + 128, kt2, Bo + 8192);
        STAGE(A, Arow0,       kt2, Ao);
        __builtin_amdgcn_s_setprio(1);
        #pragma unroll
        for (int mf = 0; mf < 4; ++mf)
            #pragma unroll
            for (int nf = 0; nf < 2; ++nf) {
                acc[mf + 4][nf] = MF(a[mf][0], b0[nf][0], acc[mf + 4][nf]);
                acc[mf + 4][nf] = MF(a[mf][1], b0[nf][1], acc[mf + 4][nf]);
            }
        __builtin_amdgcn_s_setprio(0);
        asm volatile("s_waitcnt vmcnt(6)" ::: "memory");  // tile t+1 fully retired (in-order)
        SBAR();
    }

    // ---- epilogue compute: tile NT-1 from buf[1], no staging ----
    {
        const ushort_t* Ac = As[1];
        const ushort_t* Bc = Bs[1];
        #pragma unroll
        for (int nf = 0; nf < 2; ++nf) {
            b0[nf][0] = FRAG(Bc, brow + nf * 16, 0);
            b0[nf][1] = FRAG(Bc, brow + nf * 16, 64);
            b1[nf][0] = FRAG(Bc, brow + (nf + 2) * 16, 0);
            b1[nf][1] = FRAG(Bc, brow + (nf + 2) * 16, 64);
        }
        #pragma unroll
        for (int mf = 0; mf < 4; ++mf) {
            a[mf][0] = FRAG(Ac, arow + mf * 16, 0);
            a[mf][1] = FRAG(Ac, arow + mf * 16, 64);
        }
        #pragma unroll
        for (int mf = 0; mf < 4; ++mf)
            #pragma unroll
            for (int nf = 0; nf < 2; ++nf) {
                acc[mf][nf]     = MF(a[mf][0], b0[nf][0], acc[mf][nf]);
                acc[mf][nf]     = MF(a[mf][1], b0[nf][1], acc[mf][nf]);
                acc[mf][nf + 2] = MF(a[mf][0], b1[nf][0], acc[mf][nf + 2]);
                acc[mf][nf + 2] = MF(a[mf][1], b1[nf][1], acc[mf][nf + 2]);
            }
        #pragma unroll
        for (int mf = 0; mf < 4; ++mf) {
            a[mf][0] = FRAG(Ac, arow + (mf + 4) * 16, 0);
            a[mf][1] = FRAG(Ac, arow + (mf + 4) * 16, 64);
        }
        #pragma unroll
        for (int mf = 0; mf < 4; ++mf)
            #pragma unroll
            for (int nf = 0; nf < 2; ++nf) {
                acc[mf + 4][nf]     = MF(a[mf][0], b0[nf][0], acc[mf + 4][nf]);
                acc[mf + 4][nf]     = MF(a[mf][1], b0[nf][1], acc[mf + 4][nf]);
                acc[mf + 4][nf + 2] = MF(a[mf][0], b1[nf][0], acc[mf + 4][nf + 2]);
                acc[mf + 4][nf + 2] = MF(a[mf][1], b1[nf][1], acc[mf + 4][nf + 2]);
            }
    }

    // ---- C-write: C[m][n] -> out[((s*2049 + freq)*431 + t)*2 + ri] ----
    // C/D layout: col = lane&15 (N side), row = (lane>>4)*4 + reg (M side)
    const int row_off = (lane >> 4) << 2;
    const int col_off = lane & 15;
    const int mg_base = bm * 256 + wm * 128;
    const int ng_base = bn * 256 + wn * 64;

    #pragma unroll
    for (int nf = 0; nf < 4; ++nf) {
        const int ng = ng_base + nf * 16 + col_off;
        if (ng >= N_REAL) continue;
        const int s = ng / NTIME;
        const int tt = ng - s * NTIME;
        #pragma unroll
        for (int mf = 0; mf < 8; ++mf) {
            #pragma unroll
            for (int r = 0; r < 4; ++r) {
                const int m = mg_base + mf * 16 + row_off + r;
                if (m < NFREQ) {
                    out[(((long)s * NFREQ + m) * NTIME + tt) * 2 + 0] = acc[mf][nf][r];
                } else if (m < M_REAL) {
                    out[(((long)s * NFREQ + (m - NFREQ)) * NTIME + tt) * 2 + 1] = acc[mf][nf][r];
                }
            }
        }
    }
}

extern "C" void kernel_launch(void* const* d_in, const int* in_sizes, int n_in,
                              void* d_out, int out_size, void* d_ws, size_t ws_size,
                              hipStream_t stream) {
    const float* x    = (const float*)d_in[0];
    const float* cosf = (const float*)d_in[1];
    const float* sinf = (const float*)d_in[2];
    float* out = (float*)d_out;

    ushort_t* A = (ushort_t*)d_ws;                 // 4352*4096*2 = 35.7 MB
    ushort_t* B = A + (long)M_PAD * K_DIM;         // 3584*4096*2 = 29.4 MB

    build_A_kernel<<<2048, 256, 0, stream>>>(cosf, sinf, A);
    build_B_kernel<<<2048, 256, 0, stream>>>(x, B);

    dim3 grid(M_PAD / 256, N_PAD / 256);   // 17 x 14 = 238 blocks, ~1/CU
    stft_gemm<<<grid, 512, 0, stream>>>(A, B, out);
}

// Round 4
// 142.667 us; speedup vs baseline: 1.8215x; 1.1688x over previous
//
#include <hip/hip_runtime.h>
#include <hip/hip_bf16.h>

// ---------------- problem constants ----------------
#define HOP    1024
#define NFREQ  2049
#define NTIME  431
#define SIGLEN 441000
#define N_REAL 3448           // 8*431
#define N_PAD  3584           // 14*256
#define KF     2112           // folded K: 2049 -> pad to 33*64
#define M_PADG 2304           // 9*256 rows per GEMM (2049 real)
#define MBLK   9              // M blocks per GEMM
#define NT     (KF / 64)      // 33 K-tiles of BK=64

typedef unsigned short ushort_t;
typedef unsigned int   uint_t;
typedef __attribute__((ext_vector_type(8))) __bf16 bf16x8;
typedef __attribute__((ext_vector_type(4))) float  f32x4;

// float -> bf16 (round-to-nearest-even)
__device__ __forceinline__ ushort_t f2bf(float f) {
    uint_t u = __builtin_bit_cast(uint_t, f);
    u = (u + 0x7FFFu + ((u >> 16) & 1u)) >> 16;
    return (ushort_t)u;
}

// ---------------- pack folded filters: A_even = cosf[:, :2049], A_odd = sinf[:, :2049] ----------------
// Exploits cosf[k][4096-n] = cosf[k][n], sinf[k][4096-n] = -sinf[k][n] (periodic Hann).
__global__ __launch_bounds__(256) void build_A_kernel(
        const float* __restrict__ cosf, const float* __restrict__ sinf,
        ushort_t* __restrict__ Ae, ushort_t* __restrict__ Ao) {
    const long ntask = (long)M_PADG * KF / 8;
    const long stride = (long)gridDim.x * blockDim.x;
    for (long task = (long)blockIdx.x * blockDim.x + threadIdx.x; task < ntask; task += stride) {
        const long e = task * 8;
        const int m = (int)(e / KF);
        const int k = (int)(e - (long)m * KF);
        alignas(16) ushort_t vc[8], vs[8];
        if (m < NFREQ) {
            const float* cr = cosf + ((long)m << 12) + k;   // k+7 <= 2111 < 4096, in-bounds
            const float* sr = sinf + ((long)m << 12) + k;
            #pragma unroll
            for (int j = 0; j < 8; ++j) {
                const bool ok = (k + j) <= 2048;
                vc[j] = ok ? f2bf(cr[j]) : (ushort_t)0;
                vs[j] = ok ? f2bf(sr[j]) : (ushort_t)0;
            }
        } else {
            #pragma unroll
            for (int j = 0; j < 8; ++j) { vc[j] = 0; vs[j] = 0; }
        }
        *reinterpret_cast<uint4*>(Ae + e) = *reinterpret_cast<const uint4*>(vc);
        *reinterpret_cast<uint4*>(Ao + e) = *reinterpret_cast<const uint4*>(vs);
    }
}

// ---------------- build folded frames: E[t][n]=f(n)+f(4096-n), O[t][n]=f(n)-f(4096-n) ----------------
__device__ __forceinline__ float frame_sample(const float* __restrict__ xs, int pos) {
    // pos = t*HOP + idx - 2048 in original-signal coords; reflect at both ends
    if (pos < 0) pos = -pos;
    else if (pos >= SIGLEN) pos = 2 * SIGLEN - 2 - pos;
    return xs[pos];
}

__global__ __launch_bounds__(256) void build_B_kernel(
        const float* __restrict__ x, ushort_t* __restrict__ E, ushort_t* __restrict__ O) {
    const long ntask = (long)N_PAD * KF / 8;
    const long stride = (long)gridDim.x * blockDim.x;
    for (long task = (long)blockIdx.x * blockDim.x + threadIdx.x; task < ntask; task += stride) {
        const long e = task * 8;
        const int n = (int)(e / KF);        // frame index (padded)
        const int k = (int)(e - (long)n * KF);
        alignas(16) ushort_t ve[8], vo[8];
        if (n < N_REAL) {
            const int s = n / NTIME;
            const int t = n - s * NTIME;
            const float* xs = x + (long)s * SIGLEN;
            const int base = t * HOP - 2048;
            #pragma unroll
            for (int j = 0; j < 8; ++j) {
                const int idx = k + j;                       // 0..2111
                const float fn = frame_sample(xs, base + idx);
                const bool hasm = (idx >= 1) && (idx <= 2047);
                const float fm = hasm ? frame_sample(xs, base + 4096 - idx) : 0.0f;
                ve[j] = f2bf(fn + fm);
                vo[j] = f2bf(fn - fm);
            }
        } else {
            #pragma unroll
            for (int j = 0; j < 8; ++j) { ve[j] = 0; vo[j] = 0; }
        }
        *reinterpret_cast<uint4*>(E + e) = *reinterpret_cast<const uint4*>(ve);
        *reinterpret_cast<uint4*>(O + e) = *reinterpret_cast<const uint4*>(vo);
    }
}

// ---------------- async global -> LDS (16B per lane, wave-uniform LDS base) ----------------
__device__ __forceinline__ void gload_lds16(const ushort_t* g, ushort_t* l) {
    __builtin_amdgcn_global_load_lds(
        (const __attribute__((address_space(1))) void*)g,
        (__attribute__((address_space(3))) void*)l,
        16, 0, 0);
}

__device__ __forceinline__ f32x4 MF(bf16x8 x, bf16x8 y, f32x4 c) {
    return __builtin_amdgcn_mfma_f32_16x16x32_bf16(x, y, c, 0, 0, 0);
}

#define SBAR()  __builtin_amdgcn_s_barrier()

// ---------------- 256x256 bf16 GEMM: counted-vmcnt dbuf, fine-grained lgkm overlap ----------------
// grid.x in [0,18): first 9 blocks = even/cos GEMM (real out), next 9 = odd/sin (imag out).
__global__ __launch_bounds__(512, 2) void stft_gemm(
        const ushort_t* __restrict__ Abase_all, const ushort_t* __restrict__ Bbase_all,
        float* __restrict__ out) {
    __shared__ alignas(16) ushort_t As[2][256 * 64];
    __shared__ alignas(16) ushort_t Bs[2][256 * 64];

    const int tid  = threadIdx.x;
    const int lane = tid & 63;
    const int wv   = tid >> 6;
    const int wm   = wv & 1;    // 2 (M) x 4 (N) wave grid; wave owns 128x64
    const int wn   = wv >> 1;
    const int g    = (blockIdx.x >= MBLK) ? 1 : 0;   // 0: cos->real, 1: sin->imag
    const int bm   = blockIdx.x - g * MBLK;
    const int bn   = blockIdx.y;

    const ushort_t* A = Abase_all + (long)g * M_PADG * KF;
    const ushort_t* B = Bbase_all + (long)g * N_PAD * KF;

    const long Arow0 = (long)bm * 256;
    const long Brow0 = (long)bn * 256;

    // staging: half-tile = 128 rows x 128B; thread covers rows rb and rb+64.
    // LDS dest LINEAR (tid*16B); XOR swizzle applied to GLOBAL source col.
    const int rb   = tid >> 3;                                        // 0..63
    const int scol = ((((tid & 7) << 4) ^ ((rb & 7) << 4)) >> 1);     // ushort offset in row
    const int ldsw = wv * 512;                                        // wave-uniform LDS base

    auto STAGE = [&](const ushort_t* __restrict__ G, long row0, int kt, ushort_t* half) {
        const ushort_t* gp = G + (row0 + rb) * (long)KF + kt * 64 + scol;
        gload_lds16(gp, half + ldsw);
        gload_lds16(gp + (long)64 * KF, half + 4096 + ldsw);
    };

    const int lrow = lane & 15;
    const int kq   = (lane >> 4) << 4;   // 0/16/32/48 bytes within the 64B k-step
    auto FRAG = [&](const ushort_t* buf, int lr, int kb) -> bf16x8 {
        const char* p = reinterpret_cast<const char*>(buf)
                        + lr * 128 + ((kb + kq) ^ ((lr & 7) << 4));
        return *reinterpret_cast<const bf16x8*>(p);
    };

    f32x4 acc[8][4] = {};
    bf16x8 a[4][2], b0[2][2], b1[2][2];

    const int arow = wm * 128 + lrow;
    const int brow = wn * 64 + lrow;

    // ---- prologue: tile0 fully (8 loads) + tile1's B-h0,B-h1,A-h0 (6 loads) ----
    STAGE(A, Arow0,       0, As[0]);
    STAGE(A, Arow0 + 128, 0, As[0] + 8192);
    STAGE(B, Brow0,       0, Bs[0]);
    STAGE(B, Brow0 + 128, 0, Bs[0] + 8192);
    STAGE(B, Brow0,       1, Bs[1]);
    STAGE(B, Brow0 + 128, 1, Bs[1] + 8192);
    STAGE(A, Arow0,       1, As[1]);
    asm volatile("s_waitcnt vmcnt(6)" ::: "memory");   // tile0 retired; 6 of tile1 in flight
    SBAR();

    for (int t = 0; t < NT - 1; ++t) {
        const int cur = t & 1;
        const ushort_t* Ac = As[cur];
        const ushort_t* Bc = Bs[cur];
        ushort_t* An = As[cur ^ 1];
        ushort_t* Ao = As[cur];          // tile t+2 shares parity with t
        ushort_t* Bo = Bs[cur];
        const int kt1 = t + 1;
        const int kt2 = (t + 2 < NT) ? (t + 2) : (NT - 1);   // clamped phantom at the end

        // ===== P1: issue b0, a0-3, b1 reads | stage A-h1(t+1) | Q00 (fine-grained waits)
        #pragma unroll
        for (int nf = 0; nf < 2; ++nf) {
            b0[nf][0] = FRAG(Bc, brow + nf * 16, 0);
            b0[nf][1] = FRAG(Bc, brow + nf * 16, 64);
        }
        #pragma unroll
        for (int mf = 0; mf < 4; ++mf) {
            a[mf][0] = FRAG(Ac, arow + mf * 16, 0);
            a[mf][1] = FRAG(Ac, arow + mf * 16, 64);
        }
        #pragma unroll
        for (int nf = 0; nf < 2; ++nf) {
            b1[nf][0] = FRAG(Bc, brow + (nf + 2) * 16, 0);
            b1[nf][1] = FRAG(Bc, brow + (nf + 2) * 16, 64);
        }
        STAGE(A, Arow0 + 128, kt1, An + 8192);
        __builtin_amdgcn_s_setprio(1);
        #pragma unroll
        for (int mf = 0; mf < 4; ++mf)
            #pragma unroll
            for (int nf = 0; nf < 2; ++nf) {
                acc[mf][nf] = MF(a[mf][0], b0[nf][0], acc[mf][nf]);
                acc[mf][nf] = MF(a[mf][1], b0[nf][1], acc[mf][nf]);
            }
        __builtin_amdgcn_s_setprio(0);
        SBAR();

        // ===== P2: Q01 (b1 arrived during Q00) | then refill a[] with a4-7
        __builtin_amdgcn_s_setprio(1);
        #pragma unroll
        for (int mf = 0; mf < 4; ++mf)
            #pragma unroll
            for (int nf = 0; nf < 2; ++nf) {
                acc[mf][nf + 2] = MF(a[mf][0], b1[nf][0], acc[mf][nf + 2]);
                acc[mf][nf + 2] = MF(a[mf][1], b1[nf][1], acc[mf][nf + 2]);
            }
        __builtin_amdgcn_s_setprio(0);
        #pragma unroll
        for (int mf = 0; mf < 4; ++mf) {
            a[mf][0] = FRAG(Ac, arow + (mf + 4) * 16, 0);
            a[mf][1] = FRAG(Ac, arow + (mf + 4) * 16, 64);
        }
        SBAR();

        // ===== P3: Q11 (a4-7 delivering) | architectural drain before overwrites
        __builtin_amdgcn_s_setprio(1);
        #pragma unroll
        for (int mf = 0; mf < 4; ++mf)
            #pragma unroll
            for (int nf = 0; nf < 2; ++nf) {
                acc[mf + 4][nf + 2] = MF(a[mf][0], b1[nf][0], acc[mf + 4][nf + 2]);
                acc[mf + 4][nf + 2] = MF(a[mf][1], b1[nf][1], acc[mf + 4][nf + 2]);
            }
        __builtin_amdgcn_s_setprio(0);
        asm volatile("s_waitcnt lgkmcnt(0)" ::: "memory");  // all tile-t reads delivered
        SBAR();

        // ===== P4: stage B-h0,B-h1,A-h0(t+2) | Q10 (regs only) | counted vmcnt
        STAGE(B, Brow0,       kt2, Bo);
        STAGE(B, Brow0 + 128, kt2, Bo + 8192);
        STAGE(A, Arow0,       kt2, Ao);
        __builtin_amdgcn_s_setprio(1);
        #pragma unroll
        for (int mf = 0; mf < 4; ++mf)
            #pragma unroll
            for (int nf = 0; nf < 2; ++nf) {
                acc[mf + 4][nf] = MF(a[mf][0], b0[nf][0], acc[mf + 4][nf]);
                acc[mf + 4][nf] = MF(a[mf][1], b0[nf][1], acc[mf + 4][nf]);
            }
        __builtin_amdgcn_s_setprio(0);
        asm volatile("s_waitcnt vmcnt(6)" ::: "memory");  // tile t+1 fully retired (in-order)
        SBAR();
    }

    // ---- epilogue compute: tile NT-1 from buf[(NT-1)&1], no staging ----
    {
        const ushort_t* Ac = As[(NT - 1) & 1];
        const ushort_t* Bc = Bs[(NT - 1) & 1];
        #pragma unroll
        for (int nf = 0; nf < 2; ++nf) {
            b0[nf][0] = FRAG(Bc, brow + nf * 16, 0);
            b0[nf][1] = FRAG(Bc, brow + nf * 16, 64);
            b1[nf][0] = FRAG(Bc, brow + (nf + 2) * 16, 0);
            b1[nf][1] = FRAG(Bc, brow + (nf + 2) * 16, 64);
        }
        #pragma unroll
        for (int mf = 0; mf < 4; ++mf) {
            a[mf][0] = FRAG(Ac, arow + mf * 16, 0);
            a[mf][1] = FRAG(Ac, arow + mf * 16, 64);
        }
        #pragma unroll
        for (int mf = 0; mf < 4; ++mf)
            #pragma unroll
            for (int nf = 0; nf < 2; ++nf) {
                acc[mf][nf]     = MF(a[mf][0], b0[nf][0], acc[mf][nf]);
                acc[mf][nf]     = MF(a[mf][1], b0[nf][1], acc[mf][nf]);
                acc[mf][nf + 2] = MF(a[mf][0], b1[nf][0], acc[mf][nf + 2]);
                acc[mf][nf + 2] = MF(a[mf][1], b1[nf][1], acc[mf][nf + 2]);
            }
        #pragma unroll
        for (int mf = 0; mf < 4; ++mf) {
            a[mf][0] = FRAG(Ac, arow + (mf + 4) * 16, 0);
            a[mf][1] = FRAG(Ac, arow + (mf + 4) * 16, 64);
        }
        #pragma unroll
        for (int mf = 0; mf < 4; ++mf)
            #pragma unroll
            for (int nf = 0; nf < 2; ++nf) {
                acc[mf + 4][nf]     = MF(a[mf][0], b0[nf][0], acc[mf + 4][nf]);
                acc[mf + 4][nf]     = MF(a[mf][1], b0[nf][1], acc[mf + 4][nf]);
                acc[mf + 4][nf + 2] = MF(a[mf][0], b1[nf][0], acc[mf + 4][nf + 2]);
                acc[mf + 4][nf + 2] = MF(a[mf][1], b1[nf][1], acc[mf + 4][nf + 2]);
            }
    }

    // ---- C-write: C[m][n] -> out[((s*2049 + m)*431 + t)*2 + g] ----
    // C/D layout: col = lane&15 (N side), row = (lane>>4)*4 + reg (M side)
    const int row_off = (lane >> 4) << 2;
    const int col_off = lane & 15;
    const int mg_base = bm * 256 + wm * 128;
    const int ng_base = bn * 256 + wn * 64;

    #pragma unroll
    for (int nf = 0; nf < 4; ++nf) {
        const int ng = ng_base + nf * 16 + col_off;
        if (ng >= N_REAL) continue;
        const int s = ng / NTIME;
        const int tt = ng - s * NTIME;
        #pragma unroll
        for (int mf = 0; mf < 8; ++mf) {
            #pragma unroll
            for (int r = 0; r < 4; ++r) {
                const int m = mg_base + mf * 16 + row_off + r;
                if (m < NFREQ) {
                    out[(((long)s * NFREQ + m) * NTIME + tt) * 2 + g] = acc[mf][nf][r];
                }
            }
        }
    }
}

extern "C" void kernel_launch(void* const* d_in, const int* in_sizes, int n_in,
                              void* d_out, int out_size, void* d_ws, size_t ws_size,
                              hipStream_t stream) {
    const float* x    = (const float*)d_in[0];
    const float* cosf = (const float*)d_in[1];
    const float* sinf = (const float*)d_in[2];
    float* out = (float*)d_out;

    ushort_t* Ae = (ushort_t*)d_ws;                      // 2304*2112*2B = 9.7MB
    ushort_t* Ao = Ae + (long)M_PADG * KF;               // 9.7MB
    ushort_t* E  = Ao + (long)M_PADG * KF;               // 3584*2112*2B = 15.1MB
    ushort_t* O  = E  + (long)N_PAD * KF;                // 15.1MB  (total 49.7MB)

    build_A_kernel<<<2048, 256, 0, stream>>>(cosf, sinf, Ae, Ao);
    build_B_kernel<<<2048, 256, 0, stream>>>(x, E, O);

    dim3 grid(2 * MBLK, N_PAD / 256);   // 18 x 14 = 252 blocks, ~1/CU
    stft_gemm<<<grid, 512, 0, stream>>>(Ae, E, out);
}

// Round 5
// 129.981 us; speedup vs baseline: 1.9993x; 1.0976x over previous
//
#include <hip/hip_runtime.h>
#include <hip/hip_bf16.h>

// ---------------- problem constants ----------------
#define HOP    1024
#define NFREQ  2049
#define NTIME  431
#define SIGLEN 441000
#define N_REAL 3448           // 8*431
#define N_PAD  3584           // 14*256
#define KF     2112           // folded K: 2049 -> pad to 33*64
#define M_PADG 2304           // 9*256 rows per GEMM (2049 real)
#define MBLK   9              // M blocks per GEMM
#define NPAIR  (MBLK * (N_PAD / 256))   // 126 (bm,bn) pairs per product
#define NT     (KF / 64)      // 33 K-tiles of BK=64

typedef unsigned short ushort_t;
typedef unsigned int   uint_t;
typedef __attribute__((ext_vector_type(8))) __bf16 bf16x8;
typedef __attribute__((ext_vector_type(4))) float  f32x4;

// float -> bf16 (round-to-nearest-even)
__device__ __forceinline__ ushort_t f2bf(float f) {
    uint_t u = __builtin_bit_cast(uint_t, f);
    u = (u + 0x7FFFu + ((u >> 16) & 1u)) >> 16;
    return (ushort_t)u;
}

__device__ __forceinline__ float frame_sample(const float* __restrict__ xs, int pos) {
    // pos in original-signal coords; reflect at both ends
    if (pos < 0) pos = -pos;
    else if (pos >= SIGLEN) pos = 2 * SIGLEN - 2 - pos;
    return xs[pos];
}

// ---------------- fused prep: folded filters (Ae=cos[:, :2049], Ao=sin[:, :2049])
// and folded frames (E[t][n]=f(n)+f(4096-n), O[t][n]=f(n)-f(4096-n)) ----------------
// Exploits cosf[k][4096-n] = cosf[k][n], sinf[k][4096-n] = -sinf[k][n] (periodic Hann).
__global__ __launch_bounds__(256) void build_AB_kernel(
        const float* __restrict__ cosf, const float* __restrict__ sinf,
        const float* __restrict__ x,
        ushort_t* __restrict__ Ae, ushort_t* __restrict__ Ao,
        ushort_t* __restrict__ E,  ushort_t* __restrict__ O) {
    const long ntaskA = (long)M_PADG * KF / 8;
    const long ntaskB = (long)N_PAD * KF / 8;
    const long ntask  = ntaskA + ntaskB;
    const long stride = (long)gridDim.x * blockDim.x;
    for (long task = (long)blockIdx.x * blockDim.x + threadIdx.x; task < ntask; task += stride) {
        if (task < ntaskA) {
            const long e = task * 8;
            const int m = (int)(e / KF);
            const int k = (int)(e - (long)m * KF);
            alignas(16) ushort_t vc[8], vs[8];
            if (m < NFREQ) {
                const float* cr = cosf + ((long)m << 12) + k;   // k+7 <= 2111 < 4096, in-bounds
                const float* sr = sinf + ((long)m << 12) + k;
                #pragma unroll
                for (int j = 0; j < 8; ++j) {
                    const bool ok = (k + j) <= 2048;
                    vc[j] = ok ? f2bf(cr[j]) : (ushort_t)0;
                    vs[j] = ok ? f2bf(sr[j]) : (ushort_t)0;
                }
            } else {
                #pragma unroll
                for (int j = 0; j < 8; ++j) { vc[j] = 0; vs[j] = 0; }
            }
            *reinterpret_cast<uint4*>(Ae + e) = *reinterpret_cast<const uint4*>(vc);
            *reinterpret_cast<uint4*>(Ao + e) = *reinterpret_cast<const uint4*>(vs);
        } else {
            const long e = (task - ntaskA) * 8;
            const int n = (int)(e / KF);        // frame index (padded)
            const int k = (int)(e - (long)n * KF);
            alignas(16) ushort_t ve[8], vo[8];
            if (n < N_REAL) {
                const int s = n / NTIME;
                const int t = n - s * NTIME;
                const float* xs = x + (long)s * SIGLEN;
                const int base = t * HOP - 2048;
                #pragma unroll
                for (int j = 0; j < 8; ++j) {
                    const int idx = k + j;                       // 0..2111
                    const float fn = frame_sample(xs, base + idx);
                    const bool hasm = (idx >= 1) && (idx <= 2047);
                    const float fm = hasm ? frame_sample(xs, base + 4096 - idx) : 0.0f;
                    ve[j] = f2bf(fn + fm);
                    vo[j] = f2bf(fn - fm);
                }
            } else {
                #pragma unroll
                for (int j = 0; j < 8; ++j) { ve[j] = 0; vo[j] = 0; }
            }
            *reinterpret_cast<uint4*>(E + e) = *reinterpret_cast<const uint4*>(ve);
            *reinterpret_cast<uint4*>(O + e) = *reinterpret_cast<const uint4*>(vo);
        }
    }
}

// ---------------- async global -> LDS (16B per lane, wave-uniform LDS base) ----------------
__device__ __forceinline__ void gload_lds16(const ushort_t* g, ushort_t* l) {
    __builtin_amdgcn_global_load_lds(
        (const __attribute__((address_space(1))) void*)g,
        (__attribute__((address_space(3))) void*)l,
        16, 0, 0);
}

__device__ __forceinline__ f32x4 MF(bf16x8 x, bf16x8 y, f32x4 c) {
    return __builtin_amdgcn_mfma_f32_16x16x32_bf16(x, y, c, 0, 0, 0);
}

#define SBAR()  __builtin_amdgcn_s_barrier()

// ---------------- 256x256 bf16 GEMM: counted-vmcnt dbuf, fine-grained lgkm overlap ----------------
// 1D grid of 256 blocks. Decode keeps cos/sin twins of the same (bm,bn) exactly 8 apart
// in block id -> same XCD under id%8 round-robin -> their stride-2 real/imag partial-line
// writes merge in that XCD's L2 (round-3 accidentally had this; round-4 lost it).
__global__ __launch_bounds__(512, 2) void stft_gemm(
        const ushort_t* __restrict__ Abase_all, const ushort_t* __restrict__ Bbase_all,
        float* __restrict__ out) {
    __shared__ alignas(16) ushort_t As[2][256 * 64];
    __shared__ alignas(16) ushort_t Bs[2][256 * 64];

    const int pid  = blockIdx.x;
    const int pair = ((pid >> 4) << 3) + (pid & 7);   // twin blocks (g=0/1) differ by 8 in pid
    const int g    = (pid >> 3) & 1;                  // 0: cos->real, 1: sin->imag
    if (pair >= NPAIR) return;
    const int bm   = pair % MBLK;
    const int bn   = pair / MBLK;

    const int tid  = threadIdx.x;
    const int lane = tid & 63;
    const int wv   = tid >> 6;
    const int wm   = wv & 1;    // 2 (M) x 4 (N) wave grid; wave owns 128x64
    const int wn   = wv >> 1;

    const ushort_t* A = Abase_all + (long)g * M_PADG * KF;
    const ushort_t* B = Bbase_all + (long)g * N_PAD * KF;

    const long Arow0 = (long)bm * 256;
    const long Brow0 = (long)bn * 256;

    // staging: half-tile = 128 rows x 128B; thread covers rows rb and rb+64.
    // LDS dest LINEAR (tid*16B); XOR swizzle applied to GLOBAL source col.
    const int rb   = tid >> 3;                                        // 0..63
    const int scol = ((((tid & 7) << 4) ^ ((rb & 7) << 4)) >> 1);     // ushort offset in row
    const int ldsw = wv * 512;                                        // wave-uniform LDS base

    auto STAGE = [&](const ushort_t* __restrict__ G, long row0, int kt, ushort_t* half) {
        const ushort_t* gp = G + (row0 + rb) * (long)KF + kt * 64 + scol;
        gload_lds16(gp, half + ldsw);
        gload_lds16(gp + (long)64 * KF, half + 4096 + ldsw);
    };

    const int lrow = lane & 15;
    const int kq   = (lane >> 4) << 4;   // 0/16/32/48 bytes within the 64B k-step
    auto FRAG = [&](const ushort_t* buf, int lr, int kb) -> bf16x8 {
        const char* p = reinterpret_cast<const char*>(buf)
                        + lr * 128 + ((kb + kq) ^ ((lr & 7) << 4));
        return *reinterpret_cast<const bf16x8*>(p);
    };

    f32x4 acc[8][4] = {};
    bf16x8 a[4][2], b0[2][2], b1[2][2];

    const int arow = wm * 128 + lrow;
    const int brow = wn * 64 + lrow;

    // ---- prologue: tile0 fully (8 loads) + tile1's B-h0,B-h1,A-h0 (6 loads) ----
    STAGE(A, Arow0,       0, As[0]);
    STAGE(A, Arow0 + 128, 0, As[0] + 8192);
    STAGE(B, Brow0,       0, Bs[0]);
    STAGE(B, Brow0 + 128, 0, Bs[0] + 8192);
    STAGE(B, Brow0,       1, Bs[1]);
    STAGE(B, Brow0 + 128, 1, Bs[1] + 8192);
    STAGE(A, Arow0,       1, As[1]);
    asm volatile("s_waitcnt vmcnt(6)" ::: "memory");   // tile0 retired; 6 of tile1 in flight
    SBAR();

    for (int t = 0; t < NT - 1; ++t) {
        const int cur = t & 1;
        const ushort_t* Ac = As[cur];
        const ushort_t* Bc = Bs[cur];
        ushort_t* An = As[cur ^ 1];
        ushort_t* Ao = As[cur];          // tile t+2 shares parity with t
        ushort_t* Bo = Bs[cur];
        const int kt1 = t + 1;
        const int kt2 = (t + 2 < NT) ? (t + 2) : (NT - 1);   // clamped phantom at the end

        // ===== P1: issue b0, a0-3, b1 reads | stage A-h1(t+1) | Q00 (fine-grained waits)
        #pragma unroll
        for (int nf = 0; nf < 2; ++nf) {
            b0[nf][0] = FRAG(Bc, brow + nf * 16, 0);
            b0[nf][1] = FRAG(Bc, brow + nf * 16, 64);
        }
        #pragma unroll
        for (int mf = 0; mf < 4; ++mf) {
            a[mf][0] = FRAG(Ac, arow + mf * 16, 0);
            a[mf][1] = FRAG(Ac, arow + mf * 16, 64);
        }
        #pragma unroll
        for (int nf = 0; nf < 2; ++nf) {
            b1[nf][0] = FRAG(Bc, brow + (nf + 2) * 16, 0);
            b1[nf][1] = FRAG(Bc, brow + (nf + 2) * 16, 64);
        }
        STAGE(A, Arow0 + 128, kt1, An + 8192);
        __builtin_amdgcn_s_setprio(1);
        #pragma unroll
        for (int mf = 0; mf < 4; ++mf)
            #pragma unroll
            for (int nf = 0; nf < 2; ++nf) {
                acc[mf][nf] = MF(a[mf][0], b0[nf][0], acc[mf][nf]);
                acc[mf][nf] = MF(a[mf][1], b0[nf][1], acc[mf][nf]);
            }
        __builtin_amdgcn_s_setprio(0);
        SBAR();

        // ===== P2: Q01 (b1 arrived during Q00) | then refill a[] with a4-7
        __builtin_amdgcn_s_setprio(1);
        #pragma unroll
        for (int mf = 0; mf < 4; ++mf)
            #pragma unroll
            for (int nf = 0; nf < 2; ++nf) {
                acc[mf][nf + 2] = MF(a[mf][0], b1[nf][0], acc[mf][nf + 2]);
                acc[mf][nf + 2] = MF(a[mf][1], b1[nf][1], acc[mf][nf + 2]);
            }
        __builtin_amdgcn_s_setprio(0);
        #pragma unroll
        for (int mf = 0; mf < 4; ++mf) {
            a[mf][0] = FRAG(Ac, arow + (mf + 4) * 16, 0);
            a[mf][1] = FRAG(Ac, arow + (mf + 4) * 16, 64);
        }
        SBAR();

        // ===== P3: Q11 (a4-7 delivering) | architectural drain before overwrites
        __builtin_amdgcn_s_setprio(1);
        #pragma unroll
        for (int mf = 0; mf < 4; ++mf)
            #pragma unroll
            for (int nf = 0; nf < 2; ++nf) {
                acc[mf + 4][nf + 2] = MF(a[mf][0], b1[nf][0], acc[mf + 4][nf + 2]);
                acc[mf + 4][nf + 2] = MF(a[mf][1], b1[nf][1], acc[mf + 4][nf + 2]);
            }
        __builtin_amdgcn_s_setprio(0);
        asm volatile("s_waitcnt lgkmcnt(0)" ::: "memory");  // all tile-t reads delivered
        SBAR();

        // ===== P4: stage B-h0,B-h1,A-h0(t+2) | Q10 (regs only) | counted vmcnt
        STAGE(B, Brow0,       kt2, Bo);
        STAGE(B, Brow0 + 128, kt2, Bo + 8192);
        STAGE(A, Arow0,       kt2, Ao);
        __builtin_amdgcn_s_setprio(1);
        #pragma unroll
        for (int mf = 0; mf < 4; ++mf)
            #pragma unroll
            for (int nf = 0; nf < 2; ++nf) {
                acc[mf + 4][nf] = MF(a[mf][0], b0[nf][0], acc[mf + 4][nf]);
                acc[mf + 4][nf] = MF(a[mf][1], b0[nf][1], acc[mf + 4][nf]);
            }
        __builtin_amdgcn_s_setprio(0);
        asm volatile("s_waitcnt vmcnt(6)" ::: "memory");  // tile t+1 fully retired (in-order)
        SBAR();
    }

    // ---- epilogue compute: tile NT-1 from buf[(NT-1)&1], no staging ----
    {
        const ushort_t* Ac = As[(NT - 1) & 1];
        const ushort_t* Bc = Bs[(NT - 1) & 1];
        #pragma unroll
        for (int nf = 0; nf < 2; ++nf) {
            b0[nf][0] = FRAG(Bc, brow + nf * 16, 0);
            b0[nf][1] = FRAG(Bc, brow + nf * 16, 64);
            b1[nf][0] = FRAG(Bc, brow + (nf + 2) * 16, 0);
            b1[nf][1] = FRAG(Bc, brow + (nf + 2) * 16, 64);
        }
        #pragma unroll
        for (int mf = 0; mf < 4; ++mf) {
            a[mf][0] = FRAG(Ac, arow + mf * 16, 0);
            a[mf][1] = FRAG(Ac, arow + mf * 16, 64);
        }
        #pragma unroll
        for (int mf = 0; mf < 4; ++mf)
            #pragma unroll
            for (int nf = 0; nf < 2; ++nf) {
                acc[mf][nf]     = MF(a[mf][0], b0[nf][0], acc[mf][nf]);
                acc[mf][nf]     = MF(a[mf][1], b0[nf][1], acc[mf][nf]);
                acc[mf][nf + 2] = MF(a[mf][0], b1[nf][0], acc[mf][nf + 2]);
                acc[mf][nf + 2] = MF(a[mf][1], b1[nf][1], acc[mf][nf + 2]);
            }
        #pragma unroll
        for (int mf = 0; mf < 4; ++mf) {
            a[mf][0] = FRAG(Ac, arow + (mf + 4) * 16, 0);
            a[mf][1] = FRAG(Ac, arow + (mf + 4) * 16, 64);
        }
        #pragma unroll
        for (int mf = 0; mf < 4; ++mf)
            #pragma unroll
            for (int nf = 0; nf < 2; ++nf) {
                acc[mf + 4][nf]     = MF(a[mf][0], b0[nf][0], acc[mf + 4][nf]);
                acc[mf + 4][nf]     = MF(a[mf][1], b0[nf][1], acc[mf + 4][nf]);
                acc[mf + 4][nf + 2] = MF(a[mf][0], b1[nf][0], acc[mf + 4][nf + 2]);
                acc[mf + 4][nf + 2] = MF(a[mf][1], b1[nf][1], acc[mf + 4][nf + 2]);
            }
    }

    // ---- C-write: C[m][n] -> out[((s*2049 + m)*431 + t)*2 + g] ----
    // C/D layout: col = lane&15 (N side), row = (lane>>4)*4 + reg (M side)
    const int row_off = (lane >> 4) << 2;
    const int col_off = lane & 15;
    const int mg_base = bm * 256 + wm * 128;
    const int ng_base = bn * 256 + wn * 64;

    #pragma unroll
    for (int nf = 0; nf < 4; ++nf) {
        const int ng = ng_base + nf * 16 + col_off;
        if (ng >= N_REAL) continue;
        const int s = ng / NTIME;
        const int tt = ng - s * NTIME;
        #pragma unroll
        for (int mf = 0; mf < 8; ++mf) {
            #pragma unroll
            for (int r = 0; r < 4; ++r) {
                const int m = mg_base + mf * 16 + row_off + r;
                if (m < NFREQ) {
                    out[(((long)s * NFREQ + m) * NTIME + tt) * 2 + g] = acc[mf][nf][r];
                }
            }
        }
    }
}

extern "C" void kernel_launch(void* const* d_in, const int* in_sizes, int n_in,
                              void* d_out, int out_size, void* d_ws, size_t ws_size,
                              hipStream_t stream) {
    const float* x    = (const float*)d_in[0];
    const float* cosf = (const float*)d_in[1];
    const float* sinf = (const float*)d_in[2];
    float* out = (float*)d_out;

    ushort_t* Ae = (ushort_t*)d_ws;                      // 2304*2112*2B = 9.7MB
    ushort_t* Ao = Ae + (long)M_PADG * KF;               // 9.7MB
    ushort_t* E  = Ao + (long)M_PADG * KF;               // 3584*2112*2B = 15.1MB
    ushort_t* O  = E  + (long)N_PAD * KF;                // 15.1MB  (total 49.7MB)

    build_AB_kernel<<<2048, 256, 0, stream>>>(cosf, sinf, x, Ae, Ao, E, O);

    stft_gemm<<<256, 512, 0, stream>>>(Ae, E, out);      // 1D grid; 4 blocks idle by decode
}

// Round 6
// 112.041 us; speedup vs baseline: 2.3194x; 1.1601x over previous
//
#include <hip/hip_runtime.h>
#include <hip/hip_bf16.h>

// ---------------- problem constants ----------------
#define HOP    1024
#define NFREQ  2049
#define NTIME  431
#define SIGLEN 441000
#define N_REAL 3448            // 8*431
#define MH     1025            // k rows per half-product (0..1024)
#define KH     1088            // folded half-K: 1025 -> pad to 17*64
#define NT2    17              // K-tiles per sub-GEMM
#define NTT    34              // total K-tiles per block (even + odd)
#define M_PADH 1152            // 9*128
#define MBLK2  9
#define N_PAD2 3456            // 27*128
#define NBLK2  27
#define NPAIR2 (MBLK2 * NBLK2) // 243 (bm,bn) pairs per product
#define MGRP   136             // KH/8

typedef unsigned short ushort_t;
typedef unsigned int   uint_t;
typedef __attribute__((ext_vector_type(8))) __bf16 bf16x8;
typedef __attribute__((ext_vector_type(4))) float  f32x4;

// float -> bf16 (round-to-nearest-even)
__device__ __forceinline__ ushort_t f2bf(float f) {
    uint_t u = __builtin_bit_cast(uint_t, f);
    u = (u + 0x7FFFu + ((u >> 16) & 1u)) >> 16;
    return (ushort_t)u;
}

__device__ __forceinline__ float frame_sample(const float* __restrict__ xs, int pos) {
    if (pos < 0) pos = -pos;
    else if (pos >= SIGLEN) pos = 2 * SIGLEN - 2 - pos;
    return xs[pos];
}

// ---------------- fused prep ----------------
// A[g][par][k][m]: par0 = filt_g[k][2m] (m<=1024), par1 = filt_g[k][2m+1] (m<=1023); k<1025 else 0.
// B[g][par][n][m]: g0 uses E=fn+fm, g1 uses O=fn-fm; par0 even idx=2m, par1 odd idx=2m+1.
// First-fold edges: idx=0 and idx=2048 have no mirror term.
__global__ __launch_bounds__(256) void build_prep(
        const float* __restrict__ cosf, const float* __restrict__ sinf,
        const float* __restrict__ x,
        ushort_t* __restrict__ Aall, ushort_t* __restrict__ Ball) {
    const long TA = 2L * M_PADH * MGRP;
    const long TB = (long)N_PAD2 * MGRP;
    const long stride = (long)gridDim.x * blockDim.x;
    for (long task = (long)blockIdx.x * blockDim.x + threadIdx.x; task < TA + TB; task += stride) {
        if (task < TA) {
            const int g  = (int)(task / (M_PADH * MGRP));
            const int r  = (int)(task - (long)g * (M_PADH * MGRP));
            const int k  = r / MGRP;
            const int mg = r - k * MGRP;
            const int m0 = mg * 8;
            alignas(16) ushort_t ve[8], vo[8];
            if (k < MH) {
                const float* src = (g ? sinf : cosf) + ((long)k << 12) + 2 * m0;  // cols 2m0..2m0+15 < 4096
                #pragma unroll
                for (int j = 0; j < 8; ++j) {
                    const int m = m0 + j;
                    ve[j] = (m <= 1024) ? f2bf(src[2 * j])     : (ushort_t)0;
                    vo[j] = (m <= 1023) ? f2bf(src[2 * j + 1]) : (ushort_t)0;
                }
            } else {
                #pragma unroll
                for (int j = 0; j < 8; ++j) { ve[j] = 0; vo[j] = 0; }
            }
            const long dst = ((long)(g * 2) * M_PADH + k) * KH + m0;
            *reinterpret_cast<uint4*>(Aall + dst) = *reinterpret_cast<const uint4*>(ve);
            *reinterpret_cast<uint4*>(Aall + dst + (long)M_PADH * KH) = *reinterpret_cast<const uint4*>(vo);
        } else {
            const long r = task - TA;
            const int n  = (int)(r / MGRP);
            const int mg = (int)(r - (long)n * MGRP);
            const int m0 = mg * 8;
            alignas(16) ushort_t ee[8], eo[8], oe[8], oo[8];
            if (n < N_REAL) {
                const int s = n / NTIME;
                const int t = n - s * NTIME;
                const float* xs = x + (long)s * SIGLEN;
                const int base = t * HOP - 2048;
                #pragma unroll
                for (int j = 0; j < 8; ++j) {
                    const int m = m0 + j;
                    // even lane: idx = 2m
                    const int ide = 2 * m;
                    const float fn = frame_sample(xs, base + ide);
                    const float fm = (ide >= 1 && ide <= 2047) ? frame_sample(xs, base + 4096 - ide) : 0.0f;
                    const bool oke = (m <= 1024);
                    ee[j] = oke ? f2bf(fn + fm) : (ushort_t)0;
                    oe[j] = oke ? f2bf(fn - fm) : (ushort_t)0;
                    // odd lane: idx = 2m+1
                    const int ido = 2 * m + 1;
                    const bool oko = (m <= 1023);
                    const float gn = oko ? frame_sample(xs, base + ido) : 0.0f;
                    const float gm = oko ? frame_sample(xs, base + 4096 - ido) : 0.0f;
                    eo[j] = oko ? f2bf(gn + gm) : (ushort_t)0;
                    oo[j] = oko ? f2bf(gn - gm) : (ushort_t)0;
                }
            } else {
                #pragma unroll
                for (int j = 0; j < 8; ++j) { ee[j] = 0; eo[j] = 0; oe[j] = 0; oo[j] = 0; }
            }
            const long MSZ = (long)N_PAD2 * KH;
            const long dst = (long)n * KH + m0;
            *reinterpret_cast<uint4*>(Ball + dst)           = *reinterpret_cast<const uint4*>(ee);
            *reinterpret_cast<uint4*>(Ball + dst + MSZ)     = *reinterpret_cast<const uint4*>(eo);
            *reinterpret_cast<uint4*>(Ball + dst + 2 * MSZ) = *reinterpret_cast<const uint4*>(oe);
            *reinterpret_cast<uint4*>(Ball + dst + 3 * MSZ) = *reinterpret_cast<const uint4*>(oo);
        }
    }
}

// ---------------- async global -> LDS ----------------
__device__ __forceinline__ void gload_lds16(const ushort_t* g, ushort_t* l) {
    __builtin_amdgcn_global_load_lds(
        (const __attribute__((address_space(1))) void*)g,
        (__attribute__((address_space(3))) void*)l,
        16, 0, 0);
}

__device__ __forceinline__ f32x4 MF(bf16x8 x, bf16x8 y, f32x4 c) {
    return __builtin_amdgcn_mfma_f32_16x16x32_bf16(x, y, c, 0, 0, 0);
}

#define SBAR()  __builtin_amdgcn_s_barrier()

// ---------------- 128x128 dual-bank bf16 GEMM (radix-2 combine epilogue) ----------------
// 256 threads, 4 waves (2Mx2N, wave tile 64x64), 64KB LDS -> 2 blocks/CU.
// Each block: tiles 0..16 (even samples) -> accE; 17..33 (odd) -> accO.
// Epilogue: out(k) = accE+accO ; out(2048-k) = +-(accE-accO).
__global__ __launch_bounds__(256, 2) void stft_gemm(
        const ushort_t* __restrict__ Aall, const ushort_t* __restrict__ Ball,
        float* __restrict__ out) {
    __shared__ alignas(16) ushort_t As[2][128 * 64];
    __shared__ alignas(16) ushort_t Bs[2][128 * 64];

    const int pid  = blockIdx.x;
    const int pair = ((pid >> 4) << 3) + (pid & 7);   // g=0/1 twins differ by 8 -> same XCD
    const int g    = (pid >> 3) & 1;
    if (pair >= NPAIR2) return;
    const int bm = pair % MBLK2;
    const int bn = pair / MBLK2;

    const int tid  = threadIdx.x;
    const int lane = tid & 63;
    const int wv   = tid >> 6;
    const int wm   = wv & 1;
    const int wn   = wv >> 1;

    const ushort_t* A0 = Aall + (long)(g * 2) * M_PADH * KH;   // even-sample filters
    const ushort_t* A1 = A0 + (long)M_PADH * KH;               // odd
    const ushort_t* B0 = Ball + (long)(g * 2) * N_PAD2 * KH;   // even-sample frames
    const ushort_t* B1 = B0 + (long)N_PAD2 * KH;               // odd

    const long Ar0 = (long)bm * 128;
    const long Br0 = (long)bn * 128;

    // staging: tile 128 rows x 128B; 256 threads cover 32 rows per issue.
    const int rb   = tid >> 3;                                      // 0..31
    const int scol = ((((tid & 7) << 4) ^ ((rb & 7) << 4)) >> 1);   // src-swizzled ushort col
    const int ldsw = wv * 512;                                      // wave-uniform LDS base

    auto STG = [&](const ushort_t* Gb, long r0, int kcol, ushort_t* dst, int half) {
        const ushort_t* gp = Gb + (r0 + half * 64 + rb) * (long)KH + kcol + scol;
        gload_lds16(gp,                 dst + half * 4096 + ldsw);        // rows 0-31 of half
        gload_lds16(gp + 32 * (long)KH, dst + half * 4096 + 2048 + ldsw); // rows 32-63
    };

    const int lrow = lane & 15;
    const int kq   = (lane >> 4) << 4;
    auto FRAG = [&](const ushort_t* buf, int lr, int kb) -> bf16x8 {
        const char* p = reinterpret_cast<const char*>(buf)
                        + lr * 128 + ((kb + kq) ^ ((lr & 7) << 4));
        return *reinterpret_cast<const bf16x8*>(p);
    };

    f32x4 accE[4][4] = {}, accO[4][4] = {};
    bf16x8 a[2][2], b0[2][2], b1[2][2];
    const int arow = wm * 64 + lrow;
    const int brow = wn * 64 + lrow;

    auto ABK = [&](int j, const ushort_t*& Ab, const ushort_t*& Bb, int& kc) {
        if (j >= NT2) { Ab = A1; Bb = B1; kc = (j - NT2) * 64; }
        else          { Ab = A0; Bb = B0; kc = j * 64; }
    };

    // ---- prologue: tile0 full (8 loads) + tile1 B,A-lo (6 loads) ----
    {
        const ushort_t *Ab, *Bb; int kc;
        ABK(0, Ab, Bb, kc);
        STG(Ab, Ar0, kc, As[0], 0); STG(Ab, Ar0, kc, As[0], 1);
        STG(Bb, Br0, kc, Bs[0], 0); STG(Bb, Br0, kc, Bs[0], 1);
        ABK(1, Ab, Bb, kc);
        STG(Bb, Br0, kc, Bs[1], 0); STG(Bb, Br0, kc, Bs[1], 1);
        STG(Ab, Ar0, kc, As[1], 0);
    }
    asm volatile("s_waitcnt vmcnt(6)" ::: "memory");   // tile0 retired; 6 of tile1 in flight
    SBAR();

    auto KSTEP = [&](int t, f32x4 (&acc)[4][4]) {
        const int cur = t & 1;
        const ushort_t* Ac = As[cur];
        const ushort_t* Bc = Bs[cur];
        ushort_t* An = As[cur ^ 1];
        const int j2 = (t + 2 < NTT) ? t + 2 : NTT - 1;   // clamped phantom at end
        const ushort_t *A_1, *B_1, *A_2, *B_2; int kc1, kc2;
        ABK(t + 1, A_1, B_1, kc1);
        ABK(j2,    A_2, B_2, kc2);

        // ===== P1: issue b0, a0-1, b1 | stage A-hi(t+1) | Q00
        #pragma unroll
        for (int nf = 0; nf < 2; ++nf) { b0[nf][0] = FRAG(Bc, brow + nf * 16, 0); b0[nf][1] = FRAG(Bc, brow + nf * 16, 64); }
        #pragma unroll
        for (int mf = 0; mf < 2; ++mf) { a[mf][0] = FRAG(Ac, arow + mf * 16, 0); a[mf][1] = FRAG(Ac, arow + mf * 16, 64); }
        #pragma unroll
        for (int nf = 0; nf < 2; ++nf) { b1[nf][0] = FRAG(Bc, brow + (nf + 2) * 16, 0); b1[nf][1] = FRAG(Bc, brow + (nf + 2) * 16, 64); }
        STG(A_1, Ar0, kc1, An, 1);
        __builtin_amdgcn_s_setprio(1);
        #pragma unroll
        for (int mf = 0; mf < 2; ++mf)
            #pragma unroll
            for (int nf = 0; nf < 2; ++nf) {
                acc[mf][nf] = MF(a[mf][0], b0[nf][0], acc[mf][nf]);
                acc[mf][nf] = MF(a[mf][1], b0[nf][1], acc[mf][nf]);
            }
        __builtin_amdgcn_s_setprio(0);
        SBAR();

        // ===== P2: Q01 | refill a with mf2-3
        __builtin_amdgcn_s_setprio(1);
        #pragma unroll
        for (int mf = 0; mf < 2; ++mf)
            #pragma unroll
            for (int nf = 0; nf < 2; ++nf) {
                acc[mf][nf + 2] = MF(a[mf][0], b1[nf][0], acc[mf][nf + 2]);
                acc[mf][nf + 2] = MF(a[mf][1], b1[nf][1], acc[mf][nf + 2]);
            }
        __builtin_amdgcn_s_setprio(0);
        #pragma unroll
        for (int mf = 0; mf < 2; ++mf) { a[mf][0] = FRAG(Ac, arow + (mf + 2) * 16, 0); a[mf][1] = FRAG(Ac, arow + (mf + 2) * 16, 64); }
        SBAR();

        // ===== P3: Q11 | drain tile-t reads before overwrite
        __builtin_amdgcn_s_setprio(1);
        #pragma unroll
        for (int mf = 0; mf < 2; ++mf)
            #pragma unroll
            for (int nf = 0; nf < 2; ++nf) {
                acc[mf + 2][nf + 2] = MF(a[mf][0], b1[nf][0], acc[mf + 2][nf + 2]);
                acc[mf + 2][nf + 2] = MF(a[mf][1], b1[nf][1], acc[mf + 2][nf + 2]);
            }
        __builtin_amdgcn_s_setprio(0);
        asm volatile("s_waitcnt lgkmcnt(0)" ::: "memory");
        SBAR();

        // ===== P4: stage B(j2), A-lo(j2) | Q10 | counted vmcnt
        STG(B_2, Br0, kc2, Bs[cur], 0); STG(B_2, Br0, kc2, Bs[cur], 1);
        STG(A_2, Ar0, kc2, As[cur], 0);
        __builtin_amdgcn_s_setprio(1);
        #pragma unroll
        for (int mf = 0; mf < 2; ++mf)
            #pragma unroll
            for (int nf = 0; nf < 2; ++nf) {
                acc[mf + 2][nf] = MF(a[mf][0], b0[nf][0], acc[mf + 2][nf]);
                acc[mf + 2][nf] = MF(a[mf][1], b0[nf][1], acc[mf + 2][nf]);
            }
        __builtin_amdgcn_s_setprio(0);
        asm volatile("s_waitcnt vmcnt(6)" ::: "memory");  // tile t+1 fully retired (in-order)
        SBAR();
    };

    for (int t = 0; t < NT2; ++t)        KSTEP(t, accE);   // even-sample GEMM
    for (int t = NT2; t < NTT - 1; ++t)  KSTEP(t, accO);   // odd-sample GEMM

    // ---- epilogue compute: tile 33 from buf[1] -> accO, no staging ----
    {
        const ushort_t* Ac = As[1];
        const ushort_t* Bc = Bs[1];
        #pragma unroll
        for (int nf = 0; nf < 2; ++nf) {
            b0[nf][0] = FRAG(Bc, brow + nf * 16, 0);       b0[nf][1] = FRAG(Bc, brow + nf * 16, 64);
            b1[nf][0] = FRAG(Bc, brow + (nf + 2) * 16, 0); b1[nf][1] = FRAG(Bc, brow + (nf + 2) * 16, 64);
        }
        #pragma unroll
        for (int mf = 0; mf < 2; ++mf) { a[mf][0] = FRAG(Ac, arow + mf * 16, 0); a[mf][1] = FRAG(Ac, arow + mf * 16, 64); }
        #pragma unroll
        for (int mf = 0; mf < 2; ++mf)
            #pragma unroll
            for (int nf = 0; nf < 2; ++nf) {
                accO[mf][nf]     = MF(a[mf][0], b0[nf][0], accO[mf][nf]);
                accO[mf][nf]     = MF(a[mf][1], b0[nf][1], accO[mf][nf]);
                accO[mf][nf + 2] = MF(a[mf][0], b1[nf][0], accO[mf][nf + 2]);
                accO[mf][nf + 2] = MF(a[mf][1], b1[nf][1], accO[mf][nf + 2]);
            }
        #pragma unroll
        for (int mf = 0; mf < 2; ++mf) { a[mf][0] = FRAG(Ac, arow + (mf + 2) * 16, 0); a[mf][1] = FRAG(Ac, arow + (mf + 2) * 16, 64); }
        #pragma unroll
        for (int mf = 0; mf < 2; ++mf)
            #pragma unroll
            for (int nf = 0; nf < 2; ++nf) {
                accO[mf + 2][nf]     = MF(a[mf][0], b0[nf][0], accO[mf + 2][nf]);
                accO[mf + 2][nf]     = MF(a[mf][1], b0[nf][1], accO[mf + 2][nf]);
                accO[mf + 2][nf + 2] = MF(a[mf][0], b1[nf][0], accO[mf + 2][nf + 2]);
                accO[mf + 2][nf + 2] = MF(a[mf][1], b1[nf][1], accO[mf + 2][nf + 2]);
            }
    }

    // ---- combine + write: out(k) = accE+accO ; out(2048-k) = +-(accE-accO) ----
    // C/D layout: col = lane&15 (N side), row = (lane>>4)*4 + reg (M side)
    const int row_off = (lane >> 4) << 2;
    const int col_off = lane & 15;
    const int kg  = bm * 128 + wm * 64;
    const int ng0 = bn * 128 + wn * 64;

    #pragma unroll
    for (int nf = 0; nf < 4; ++nf) {
        const int ng = ng0 + nf * 16 + col_off;
        if (ng >= N_REAL) continue;
        const int s  = ng / NTIME;
        const int tt = ng - s * NTIME;
        const long rowbase = (long)s * NFREQ * NTIME;
        #pragma unroll
        for (int mf = 0; mf < 4; ++mf) {
            #pragma unroll
            for (int r = 0; r < 4; ++r) {
                const int k = kg + mf * 16 + row_off + r;
                if (k < MH) {
                    const float vE = accE[mf][nf][r];
                    const float vO = accO[mf][nf][r];
                    const float vP = vE + vO;
                    const float vM = g ? (vO - vE) : (vE - vO);
                    out[(rowbase + (long)k * NTIME + tt) * 2 + g]            = vP;
                    out[(rowbase + (long)(2048 - k) * NTIME + tt) * 2 + g]   = vM;
                }
            }
        }
    }
}

extern "C" void kernel_launch(void* const* d_in, const int* in_sizes, int n_in,
                              void* d_out, int out_size, void* d_ws, size_t ws_size,
                              hipStream_t stream) {
    const float* x    = (const float*)d_in[0];
    const float* cosf = (const float*)d_in[1];
    const float* sinf = (const float*)d_in[2];
    float* out = (float*)d_out;

    ushort_t* Aall = (ushort_t*)d_ws;                     // 4 * 1152*1088*2B = 10.0MB
    ushort_t* Ball = Aall + 4L * M_PADH * KH;             // 4 * 3456*1088*2B = 30.1MB

    build_prep<<<2048, 256, 0, stream>>>(cosf, sinf, x, Aall, Ball);

    // 486 active blocks (243 pairs x 2 products), padded to full 16-chunks for twin decode
    stft_gemm<<<496, 256, 0, stream>>>(Aall, Ball, out);
}

// Round 7
// 84.546 us; speedup vs baseline: 3.0737x; 1.3252x over previous
//
#include <hip/hip_runtime.h>
#include <hip/hip_bf16.h>

// ---------------- problem constants ----------------
#define HOP    1024
#define NFREQ  2049
#define NTIME  431
#define SIGLEN 441000
#define N_REAL 3448            // 8*431
#define MH     1025            // k rows per half-product (0..1024)
#define KH     1088            // folded half-K: 1025 -> pad to 17*64
#define NT2    17              // K-tiles per sub-GEMM
#define NTT    34              // total K-tiles per block (even + odd)
#define M_PADH 1152            // 9*128
#define MBLK2  9
#define N_PAD2 3456            // 27*128
#define NBLK2  27
#define NPAIR2 (MBLK2 * NBLK2) // 243 (bm,bn) pairs per product
#define MGRP   136             // KH/8

typedef unsigned short ushort_t;
typedef unsigned int   uint_t;
typedef __attribute__((ext_vector_type(8))) __bf16 bf16x8;
typedef __attribute__((ext_vector_type(4))) float  f32x4;

// float -> bf16 (round-to-nearest-even)
__device__ __forceinline__ ushort_t f2bf(float f) {
    uint_t u = __builtin_bit_cast(uint_t, f);
    u = (u + 0x7FFFu + ((u >> 16) & 1u)) >> 16;
    return (ushort_t)u;
}

__device__ __forceinline__ float frame_sample(const float* __restrict__ xs, int pos) {
    if (pos < 0) pos = -pos;
    else if (pos >= SIGLEN) pos = 2 * SIGLEN - 2 - pos;
    return xs[pos];
}

// ---------------- fused prep (vectorized) ----------------
// A[g][par][k][m]: par0 = filt_g[k][2m] (m<=1024), par1 = filt_g[k][2m+1] (m<=1023); k<1025 else 0.
// B[g][par][n][m]: g0 uses E=fn+fm, g1 uses O=fn-fm; par0 idx=2m, par1 idx=2m+1.
__global__ __launch_bounds__(256) void build_prep(
        const float* __restrict__ cosf, const float* __restrict__ sinf,
        const float* __restrict__ x,
        ushort_t* __restrict__ Aall, ushort_t* __restrict__ Ball) {
    const long TA = 2L * M_PADH * MGRP;
    const long TB = (long)N_PAD2 * MGRP;
    const long stride = (long)gridDim.x * blockDim.x;
    for (long task = (long)blockIdx.x * blockDim.x + threadIdx.x; task < TA + TB; task += stride) {
        if (task < TA) {
            const int g  = (int)(task / (M_PADH * MGRP));
            const int r  = (int)(task - (long)g * (M_PADH * MGRP));
            const int k  = r / MGRP;
            const int mg = r - k * MGRP;
            const int m0 = mg * 8;
            alignas(16) ushort_t ve[8], vo[8];
            #pragma unroll
            for (int j = 0; j < 8; ++j) { ve[j] = 0; vo[j] = 0; }
            if (k < MH && mg <= 127) {
                const float* src = (g ? sinf : cosf) + ((long)k << 12) + 2 * m0;  // 64B aligned
                const float4 f0 = ((const float4*)src)[0];
                const float4 f1 = ((const float4*)src)[1];
                const float4 f2 = ((const float4*)src)[2];
                const float4 f3 = ((const float4*)src)[3];
                const float fe[8] = {f0.x,f0.z,f1.x,f1.z,f2.x,f2.z,f3.x,f3.z};
                const float fo[8] = {f0.y,f0.w,f1.y,f1.w,f2.y,f2.w,f3.y,f3.w};
                #pragma unroll
                for (int j = 0; j < 8; ++j) { ve[j] = f2bf(fe[j]); vo[j] = f2bf(fo[j]); }
            } else if (k < MH && mg == 128) {
                const float* src = (g ? sinf : cosf) + ((long)k << 12);
                ve[0] = f2bf(src[2048]);     // m=1024 even col only
            }
            const long dst = ((long)(g * 2) * M_PADH + k) * KH + m0;
            *reinterpret_cast<uint4*>(Aall + dst) = *reinterpret_cast<const uint4*>(ve);
            *reinterpret_cast<uint4*>(Aall + dst + (long)M_PADH * KH) = *reinterpret_cast<const uint4*>(vo);
        } else {
            const long r = task - TA;
            const int n  = (int)(r / MGRP);
            const int mg = (int)(r - (long)n * MGRP);
            const int m0 = mg * 8;
            alignas(16) ushort_t ee[8], eo[8], oe[8], oo[8];
            #pragma unroll
            for (int j = 0; j < 8; ++j) { ee[j] = 0; eo[j] = 0; oe[j] = 0; oo[j] = 0; }
            if (n < N_REAL) {
                const int s = n / NTIME;
                const int t = n - s * NTIME;
                const float* xs = x + (long)s * SIGLEN;
                const int base = t * HOP - 2048;
                const bool interior = (t >= 2) && (t <= 428);
                if (interior && mg <= 127) {
                    // forward 16 floats (64B aligned), mirror 17 floats (64B aligned)
                    const float* fp = xs + base + 2 * m0;
                    const float4 f0 = ((const float4*)fp)[0];
                    const float4 f1 = ((const float4*)fp)[1];
                    const float4 f2 = ((const float4*)fp)[2];
                    const float4 f3 = ((const float4*)fp)[3];
                    const float fe[8] = {f0.x,f0.z,f1.x,f1.z,f2.x,f2.z,f3.x,f3.z};
                    const float fo[8] = {f0.y,f0.w,f1.y,f1.w,f2.y,f2.w,f3.y,f3.w};
                    const float* gp = xs + base + 4096 - 2 * m0 - 16;
                    const float4 h0 = ((const float4*)gp)[0];
                    const float4 h1 = ((const float4*)gp)[1];
                    const float4 h2 = ((const float4*)gp)[2];
                    const float4 h3 = ((const float4*)gp)[3];
                    const float h16 = gp[16];
                    const float hh[17] = {h0.x,h0.y,h0.z,h0.w, h1.x,h1.y,h1.z,h1.w,
                                          h2.x,h2.y,h2.z,h2.w, h3.x,h3.y,h3.z,h3.w, h16};
                    #pragma unroll
                    for (int j = 0; j < 8; ++j) {
                        const float me = hh[16 - 2 * j];   // x[base+4096-2m]
                        const float mo = hh[15 - 2 * j];   // x[base+4096-2m-1]
                        ee[j] = f2bf(fe[j] + me);
                        oe[j] = f2bf(fe[j] - me);
                        eo[j] = f2bf(fo[j] + mo);
                        oo[j] = f2bf(fo[j] - mo);
                    }
                    if (mg == 0) {   // m=0: ide=0 has no mirror term
                        ee[0] = f2bf(fe[0]);
                        oe[0] = f2bf(fe[0]);
                    }
                } else if (mg <= 128) {
                    // scalar fallback: edge frames + the m=1024 column
                    #pragma unroll
                    for (int j = 0; j < 8; ++j) {
                        const int m = m0 + j;
                        const int ide = 2 * m;
                        if (m <= 1024) {
                            const float fn = frame_sample(xs, base + ide);
                            const float fm = (ide >= 1 && ide <= 2047) ? frame_sample(xs, base + 4096 - ide) : 0.0f;
                            ee[j] = f2bf(fn + fm);
                            oe[j] = f2bf(fn - fm);
                        }
                        if (m <= 1023) {
                            const int ido = 2 * m + 1;
                            const float gn = frame_sample(xs, base + ido);
                            const float gm = frame_sample(xs, base + 4096 - ido);
                            eo[j] = f2bf(gn + gm);
                            oo[j] = f2bf(gn - gm);
                        }
                    }
                }
            }
            const long MSZ = (long)N_PAD2 * KH;
            const long dst = (long)n * KH + m0;
            *reinterpret_cast<uint4*>(Ball + dst)           = *reinterpret_cast<const uint4*>(ee);
            *reinterpret_cast<uint4*>(Ball + dst + MSZ)     = *reinterpret_cast<const uint4*>(eo);
            *reinterpret_cast<uint4*>(Ball + dst + 2 * MSZ) = *reinterpret_cast<const uint4*>(oe);
            *reinterpret_cast<uint4*>(Ball + dst + 3 * MSZ) = *reinterpret_cast<const uint4*>(oo);
        }
    }
}

// ---------------- async global -> LDS ----------------
__device__ __forceinline__ void gload_lds16(const ushort_t* g, ushort_t* l) {
    __builtin_amdgcn_global_load_lds(
        (const __attribute__((address_space(1))) void*)g,
        (__attribute__((address_space(3))) void*)l,
        16, 0, 0);
}

__device__ __forceinline__ f32x4 MF(bf16x8 x, bf16x8 y, f32x4 c) {
    return __builtin_amdgcn_mfma_f32_16x16x32_bf16(x, y, c, 0, 0, 0);
}

#define SBAR()  __builtin_amdgcn_s_barrier()
#define SCHED() __builtin_amdgcn_sched_barrier(0)

// ---------------- 128x128 dual-bank bf16 GEMM, 2-barrier K-loop ----------------
// 256 threads, 4 waves (2Mx2N, wave tile 64x64), 64KB LDS -> 2 blocks/CU.
// Per tile: {16 ds_read + 32 MFMA} lgkm0+SBAR {stage t+2 -> cur} vmcnt(8) SBAR.
// Tiles 0..16 (even samples) -> accE; 17..33 (odd) -> accO.
__global__ __launch_bounds__(256, 2) void stft_gemm(
        const ushort_t* __restrict__ Aall, const ushort_t* __restrict__ Ball,
        float* __restrict__ out) {
    __shared__ alignas(16) ushort_t As[2][128 * 64];
    __shared__ alignas(16) ushort_t Bs[2][128 * 64];

    const int pid  = blockIdx.x;
    const int pair = ((pid >> 4) << 3) + (pid & 7);   // g=0/1 twins differ by 8 -> same XCD
    const int g    = (pid >> 3) & 1;
    if (pair >= NPAIR2) return;
    const int bm = pair % MBLK2;
    const int bn = pair / MBLK2;

    const int tid  = threadIdx.x;
    const int lane = tid & 63;
    const int wv   = tid >> 6;
    const int wm   = wv & 1;
    const int wn   = wv >> 1;

    const ushort_t* A0 = Aall + (long)(g * 2) * M_PADH * KH;   // even-sample filters
    const ushort_t* A1 = A0 + (long)M_PADH * KH;               // odd
    const ushort_t* B0 = Ball + (long)(g * 2) * N_PAD2 * KH;   // even-sample frames
    const ushort_t* B1 = B0 + (long)N_PAD2 * KH;               // odd

    const long Ar0 = (long)bm * 128;
    const long Br0 = (long)bn * 128;

    const int rb   = tid >> 3;                                      // 0..31
    const int scol = ((((tid & 7) << 4) ^ ((rb & 7) << 4)) >> 1);   // src-swizzled ushort col
    const int ldsw = wv * 512;                                      // wave-uniform LDS base

    auto STG = [&](const ushort_t* Gb, long r0, int kcol, ushort_t* dst, int half) {
        const ushort_t* gp = Gb + (r0 + half * 64 + rb) * (long)KH + kcol + scol;
        gload_lds16(gp,                 dst + half * 4096 + ldsw);
        gload_lds16(gp + 32 * (long)KH, dst + half * 4096 + 2048 + ldsw);
    };

    const int lrow = lane & 15;
    const int kq   = (lane >> 4) << 4;
    auto FRAG = [&](const ushort_t* buf, int lr, int kb) -> bf16x8 {
        const char* p = reinterpret_cast<const char*>(buf)
                        + lr * 128 + ((kb + kq) ^ ((lr & 7) << 4));
        return *reinterpret_cast<const bf16x8*>(p);
    };

    f32x4 accE[4][4] = {}, accO[4][4] = {};
    bf16x8 a[4][2], b[4][2];
    const int arow = wm * 64 + lrow;
    const int brow = wn * 64 + lrow;

    auto ABK = [&](int j, const ushort_t*& Ab, const ushort_t*& Bb, int& kc) {
        if (j >= NT2) { Ab = A1; Bb = B1; kc = (j - NT2) * 64; }
        else          { Ab = A0; Bb = B0; kc = j * 64; }
    };

    // ---- prologue: tile0 -> buf0, tile1 -> buf1 (8 loads each) ----
    {
        const ushort_t *Ab, *Bb; int kc;
        ABK(0, Ab, Bb, kc);
        STG(Ab, Ar0, kc, As[0], 0); STG(Ab, Ar0, kc, As[0], 1);
        STG(Bb, Br0, kc, Bs[0], 0); STG(Bb, Br0, kc, Bs[0], 1);
        ABK(1, Ab, Bb, kc);
        STG(Ab, Ar0, kc, As[1], 0); STG(Ab, Ar0, kc, As[1], 1);
        STG(Bb, Br0, kc, Bs[1], 0); STG(Bb, Br0, kc, Bs[1], 1);
    }
    asm volatile("s_waitcnt vmcnt(8)" ::: "memory");   // tile0's 8 retired (in-order)
    SBAR();

    auto ITER = [&](int t, f32x4 (&acc)[4][4]) {
        const int cur = t & 1;
        const ushort_t* Ac = As[cur];
        const ushort_t* Bc = Bs[cur];

        // 16 frag reads; compiler interleaves MFMAs with fine-grained lgkmcnt
        #pragma unroll
        for (int mf = 0; mf < 4; ++mf) {
            a[mf][0] = FRAG(Ac, arow + mf * 16, 0);
            a[mf][1] = FRAG(Ac, arow + mf * 16, 64);
        }
        #pragma unroll
        for (int nf = 0; nf < 4; ++nf) {
            b[nf][0] = FRAG(Bc, brow + nf * 16, 0);
            b[nf][1] = FRAG(Bc, brow + nf * 16, 64);
        }
        __builtin_amdgcn_s_setprio(1);
        #pragma unroll
        for (int mf = 0; mf < 4; ++mf)
            #pragma unroll
            for (int nf = 0; nf < 4; ++nf) {
                acc[mf][nf] = MF(a[mf][0], b[nf][0], acc[mf][nf]);
                acc[mf][nf] = MF(a[mf][1], b[nf][1], acc[mf][nf]);
            }
        __builtin_amdgcn_s_setprio(0);
        // all reads of cur delivered (wave) -> barrier (block) -> safe to overwrite cur
        asm volatile("s_waitcnt lgkmcnt(0)" ::: "memory");
        SCHED();
        SBAR();
        if (t + 2 < NTT) {
            const ushort_t *A_2, *B_2; int kc2;
            ABK(t + 2, A_2, B_2, kc2);
            STG(A_2, Ar0, kc2, As[cur], 0); STG(A_2, Ar0, kc2, As[cur], 1);
            STG(B_2, Br0, kc2, Bs[cur], 0); STG(B_2, Br0, kc2, Bs[cur], 1);
            asm volatile("s_waitcnt vmcnt(8)" ::: "memory");   // t+1's 8 retired
        } else if (t + 1 < NTT) {
            asm volatile("s_waitcnt vmcnt(0)" ::: "memory");   // last prefetch retired
        }
        if (t + 1 < NTT) SBAR();
    };

    for (int t = 0; t < NT2; ++t)   ITER(t, accE);   // even-sample GEMM
    for (int t = NT2; t < NTT; ++t) ITER(t, accO);   // odd-sample GEMM

    // ---- combine + write: out(k) = accE+accO ; out(2048-k) = +-(accE-accO) ----
    // C/D layout: col = lane&15 (N side), row = (lane>>4)*4 + reg (M side)
    const int row_off = (lane >> 4) << 2;
    const int col_off = lane & 15;
    const int kg  = bm * 128 + wm * 64;
    const int ng0 = bn * 128 + wn * 64;

    #pragma unroll
    for (int nf = 0; nf < 4; ++nf) {
        const int ng = ng0 + nf * 16 + col_off;
        if (ng >= N_REAL) continue;
        const int s  = ng / NTIME;
        const int tt = ng - s * NTIME;
        const long rowbase = (long)s * NFREQ * NTIME;
        #pragma unroll
        for (int mf = 0; mf < 4; ++mf) {
            #pragma unroll
            for (int r = 0; r < 4; ++r) {
                const int k = kg + mf * 16 + row_off + r;
                if (k < MH) {
                    const float vE = accE[mf][nf][r];
                    const float vO = accO[mf][nf][r];
                    const float vP = vE + vO;
                    const float vM = g ? (vO - vE) : (vE - vO);
                    out[(rowbase + (long)k * NTIME + tt) * 2 + g]          = vP;
                    out[(rowbase + (long)(2048 - k) * NTIME + tt) * 2 + g] = vM;
                }
            }
        }
    }
}

extern "C" void kernel_launch(void* const* d_in, const int* in_sizes, int n_in,
                              void* d_out, int out_size, void* d_ws, size_t ws_size,
                              hipStream_t stream) {
    const float* x    = (const float*)d_in[0];
    const float* cosf = (const float*)d_in[1];
    const float* sinf = (const float*)d_in[2];
    float* out = (float*)d_out;

    ushort_t* Aall = (ushort_t*)d_ws;                     // 4 * 1152*1088*2B = 10.0MB
    ushort_t* Ball = Aall + 4L * M_PADH * KH;             // 4 * 3456*1088*2B = 30.1MB

    build_prep<<<2048, 256, 0, stream>>>(cosf, sinf, x, Aall, Ball);

    // 486 active blocks (243 pairs x 2 products), padded for twin decode
    stft_gemm<<<496, 256, 0, stream>>>(Aall, Ball, out);
}